// Round 2
// baseline (342.969 us; speedup 1.0000x reference)
//
#include <hip/hip_runtime.h>
#include <math.h>

typedef __attribute__((ext_vector_type(8))) short  short8;
typedef __attribute__((ext_vector_type(4))) float  f32x4;
typedef __attribute__((ext_vector_type(4))) unsigned short u16x4;
typedef __attribute__((ext_vector_type(8))) unsigned short u16x8;
typedef unsigned short u16;

#define B_     2
#define NQ_    1024
#define NK_    8192
#define DIM_   512
#define H_     8
#define DH_    64
#define EPS_   1e-5f
#define SCALE_ 0.125f
#define SPLITS 4

__device__ __forceinline__ u16 f2bf(float f) {
  unsigned int u = __float_as_uint(f);
  u += 0x7fffu + ((u >> 16) & 1u);
  return (u16)(u >> 16);
}

// ---------------------------------------------------------------- weight transpose+cast
// WT[n][k] = (bf16) W[k][n].  K=512 for all three weights.
__global__ __launch_bounds__(256) void wt_kernel(
    const float* __restrict__ wq, const float* __restrict__ wkv,
    const float* __restrict__ wout,
    u16* __restrict__ wqT, u16* __restrict__ wkvT, u16* __restrict__ woutT) {
  __shared__ float tile[64][65];
  int bid = blockIdx.x;
  const float* W; u16* WT; int N; int tix;
  if (bid < 64)       { W = wq;   WT = wqT;   N = 512;  tix = bid; }
  else if (bid < 192) { W = wkv;  WT = wkvT;  N = 1024; tix = bid - 64; }
  else                { W = wout; WT = woutT; N = 512;  tix = bid - 192; }
  int ntn = N >> 6;
  int k0 = (tix / ntn) << 6, n0 = (tix % ntn) << 6;
  int t = threadIdx.x;
  {
    int kk = t >> 2, nc = (t & 3) << 4;
#pragma unroll
    for (int i = 0; i < 4; ++i) {
      f32x4 v = *(const f32x4*)&W[(size_t)(k0 + kk) * N + n0 + nc + 4 * i];
      tile[kk][nc + 4*i + 0] = v[0];
      tile[kk][nc + 4*i + 1] = v[1];
      tile[kk][nc + 4*i + 2] = v[2];
      tile[kk][nc + 4*i + 3] = v[3];
    }
  }
  __syncthreads();
  {
    int n = t >> 2, kc = (t & 3) << 4;
#pragma unroll
    for (int i = 0; i < 2; ++i) {
      u16x8 o;
#pragma unroll
      for (int j = 0; j < 8; ++j) o[j] = f2bf(tile[kc + 8*i + j][n]);
      *(u16x8*)&WT[(size_t)(n0 + n) * 512 + k0 + kc + 8*i] = o;
    }
  }
}

// ---------------------------------------------------------------- LN -> bf16 (fused stats+normalize)
__global__ __launch_bounds__(256) void ln_kernel(
    const float* __restrict__ xq, const float* __restrict__ xc,
    const float* __restrict__ nw, const float* __restrict__ nb,
    const float* __restrict__ ncw, const float* __restrict__ ncb,
    u16* __restrict__ xqb, u16* __restrict__ xcb) {
  int wid = threadIdx.x >> 6, lane = threadIdx.x & 63;
  int row = blockIdx.x * 4 + wid;
  const float* x; const float* w; const float* bb; u16* o; int r;
  if (row < 2048) { x = xq; w = nw;  bb = nb;  o = xqb; r = row; }
  else            { x = xc; w = ncw; bb = ncb; o = xcb; r = row - 2048; }
  const f32x4* px = (const f32x4*)(x + (size_t)r * 512);
  f32x4 v0 = px[lane], v1 = px[lane + 64];
  float s  = v0[0]+v0[1]+v0[2]+v0[3] + v1[0]+v1[1]+v1[2]+v1[3];
  float ss = v0[0]*v0[0]+v0[1]*v0[1]+v0[2]*v0[2]+v0[3]*v0[3]
           + v1[0]*v1[0]+v1[1]*v1[1]+v1[2]*v1[2]+v1[3]*v1[3];
#pragma unroll
  for (int ofs = 32; ofs >= 1; ofs >>= 1) { s += __shfl_xor(s, ofs); ss += __shfl_xor(ss, ofs); }
  float mu = s * (1.f/512.f);
  float var = ss * (1.f/512.f) - mu*mu;
  float rs = rsqrtf(var + EPS_);
  const f32x4* pw = (const f32x4*)w; const f32x4* pb = (const f32x4*)bb;
#pragma unroll
  for (int seg = 0; seg < 2; ++seg) {
    int e4 = lane + 64*seg;
    f32x4 xv = seg ? v1 : v0;
    f32x4 wv = pw[e4], bv = pb[e4];
    u16x4 ov;
#pragma unroll
    for (int c = 0; c < 4; ++c) ov[c] = f2bf((xv[c]-mu)*rs*wv[c] + bv[c]);
    *(u16x4*)&o[(size_t)r*512 + e4*4] = ov;
  }
}

// ---------------------------------------------------------------- trig tables (fp32)
__global__ __launch_bounds__(256) void trig_kernel(
    const float* __restrict__ rq, const float* __restrict__ rc,
    float* __restrict__ cq, float* __restrict__ sq,
    float* __restrict__ cc, float* __restrict__ sc) {
  int i = blockIdx.x * 256 + threadIdx.x;
  const int NQE = B_*NQ_*DH_;   // 131072
  const int NCE = B_*NK_*DH_;   // 1048576
  if (i < NQE) { float s, c; sincosf(rq[i], &s, &c); cq[i] = c; sq[i] = s; }
  if (i < NCE) { float s, c; sincosf(rc[i], &s, &c); cc[i] = c; sc[i] = s; }
}

// ---------------------------------------------------------------- MFMA GEMM
// MODE 0: xqb(2048x512) x wqT   -> rope+ -> qb  (bh,seq,dh) bf16
// MODE 1: xcb(16384x512) x wkvT -> rope+ -> kb, vb
// MODE 2: aob(remap 2048x512) x woutT + bias -> d_out fp32
template<int MODE>
__global__ __launch_bounds__(256) void gemm_mfma(
    const u16* __restrict__ Abf, const u16* __restrict__ WT,
    const float* __restrict__ ctab, const float* __restrict__ stab,
    const float* __restrict__ bias,
    u16* __restrict__ out0, u16* __restrict__ out1, float* __restrict__ outf) {
  constexpr int BM   = (MODE==1) ? 128 : 64;
  constexpr int MR   = (MODE==1) ? 2 : 1;
  constexpr int NR   = (MODE==1) ? 8 : 4;
  constexpr int N    = (MODE==1) ? 1024 : 512;
  constexpr int NSEQ = (MODE==1) ? 8192 : 1024;
  constexpr int NBN  = N / BM;           // BN == BM in all modes
  __shared__ u16 As[BM*64];
  __shared__ u16 Bs[BM*64];
  const int tid = threadIdx.x;
  const int w = tid >> 6, l = tid & 63;
  const int la = l >> 4, lb = l & 15;
  const int m0 = (blockIdx.x / NBN) * BM;
  const int n0 = (blockIdx.x % NBN) * BM;
  f32x4 acc[MR][NR];
#pragma unroll
  for (int i = 0; i < MR; ++i)
#pragma unroll
    for (int j = 0; j < NR; ++j) acc[i][j] = (f32x4){0.f,0.f,0.f,0.f};

  for (int k0 = 0; k0 < 512; k0 += 64) {
    if (k0) __syncthreads();
    {
      constexpr int TPR = 256 / BM;
      constexpr int GPT = 8 / TPR;
      int row = tid / TPR;
      int g0 = (tid % TPR) * GPT;
#pragma unroll
      for (int i = 0; i < GPT; ++i) {
        int g = g0 + i;
        short8 av;
        if (MODE == 2) {
          int kk = k0 + g*8;
          int m = m0 + row;
          av = *(const short8*)&Abf[((size_t)((m >> 10)*H_ + (kk >> 6)) * NQ_ + (m & 1023)) * 64 + (kk & 63)];
        } else {
          av = *(const short8*)&Abf[(size_t)(m0 + row) * 512 + k0 + g*8];
        }
        *(short8*)&As[row*64 + ((g ^ (row & 7)) << 3)] = av;
        short8 bv = *(const short8*)&WT[(size_t)(n0 + row) * 512 + k0 + g*8];
        *(short8*)&Bs[row*64 + ((g ^ (row & 7)) << 3)] = bv;
      }
    }
    __syncthreads();
#pragma unroll
    for (int h = 0; h < 2; ++h) {
      short8 af[MR], bf[NR];
#pragma unroll
      for (int i = 0; i < MR; ++i) {
        int row = w*(16*MR) + i*16 + lb;
        int g = (4*h + la) ^ (row & 7);
        af[i] = *(const short8*)&As[row*64 + g*8];
      }
#pragma unroll
      for (int j = 0; j < NR; ++j) {
        int row = j*16 + lb;
        int g = (4*h + la) ^ (row & 7);
        bf[j] = *(const short8*)&Bs[row*64 + g*8];
      }
#pragma unroll
      for (int i = 0; i < MR; ++i)
#pragma unroll
        for (int j = 0; j < NR; ++j)
          acc[i][j] = __builtin_amdgcn_mfma_f32_16x16x32_bf16(af[i], bf[j], acc[i][j], 0, 0, 0);
    }
  }

  // epilogue
#pragma unroll
  for (int i = 0; i < MR; ++i) {
#pragma unroll
    for (int j = 0; j < NR; ++j) {
      int n = n0 + 16*j + lb;
#pragma unroll
      for (int r = 0; r < 4; ++r) {
        int m = m0 + w*(16*MR) + 16*i + 4*la + r;
        float x = acc[i][j][r];
        if (MODE == 2) {
          outf[(size_t)m * 512 + n] = x + bias[n];
        } else {
          float pr = __shfl_xor(x, 1);
          int e  = (MODE == 1 && n >= 512) ? n - 512 : n;
          int hh = e >> 6, dh = e & 63;
          float cv = ctab[(size_t)m * 64 + dh];
          float sv = stab[(size_t)m * 64 + dh];
          float y = x * cv + ((n & 1) ? pr * sv : -pr * sv);
          int bI = m / NSEQ, seq = m % NSEQ;
          u16* dst = (MODE == 1 && n >= 512) ? out1 : out0;
          dst[((size_t)(bI*H_ + hh) * NSEQ + seq) * 64 + dh] = f2bf(y);
        }
      }
    }
  }
}

// ---------------------------------------------------------------- attention (MFMA, K-split flash)
// grid = 16 bh * 16 qtiles * SPLITS. Block: 4 waves, each wave owns 16 q-rows.
__global__ __launch_bounds__(256) void attn_mfma(
    const u16* __restrict__ qb, const u16* __restrict__ kb,
    const u16* __restrict__ vb, const int* __restrict__ mask,
    float* __restrict__ Opart, float* __restrict__ mpart, float* __restrict__ lpart) {
  __shared__ u16 Ks[64*64];
  __shared__ u16 Vt[64*64];
  __shared__ u16 Ps[4*16*64];
  __shared__ float Msk[64];
  const int bid = blockIdx.x;
  const int s  = bid & (SPLITS-1);
  const int qt = (bid >> 2) & 15;
  const int bh = bid >> 6;
  const int bI = bh >> 3;
  const int tid = threadIdx.x;
  const int w = tid >> 6, l = tid & 63;
  const int la = l >> 4, lb = l & 15;
  const int qrow = qt*64 + w*16 + lb;
  short8 qf[2];
  qf[0] = *(const short8*)&qb[(((size_t)bh * NQ_) + qrow) * 64 + 8*la];
  qf[1] = *(const short8*)&qb[(((size_t)bh * NQ_) + qrow) * 64 + 32 + 8*la];
  f32x4 accO[4];
#pragma unroll
  for (int j = 0; j < 4; ++j) accO[j] = (f32x4){0.f,0.f,0.f,0.f};
  float mrow[4] = {-1e30f,-1e30f,-1e30f,-1e30f};
  float lrow[4] = {0.f,0.f,0.f,0.f};
  const int key0 = s * (NK_/SPLITS);

  for (int kt = 0; kt < (NK_/SPLITS)/64; ++kt) {
    const int kbase = key0 + kt*64;
    __syncthreads();
    {
      int row = tid >> 2;
      int g0 = (tid & 3) * 2;
      const u16* ksrc = &kb[((size_t)bh * NK_ + kbase + row) * 64];
      const u16* vsrc = &vb[((size_t)bh * NK_ + kbase + row) * 64];
#pragma unroll
      for (int i = 0; i < 2; ++i) {
        int g = g0 + i;
        short8 kv = *(const short8*)&ksrc[g*8];
        *(short8*)&Ks[row*64 + ((g ^ (row & 7)) << 3)] = kv;
        short8 vv = *(const short8*)&vsrc[g*8];
#pragma unroll
        for (int j = 0; j < 8; ++j) {
          int d = g*8 + j;
          Vt[d*64 + ((((row >> 3) ^ (d & 7)) << 3) | (row & 7))] = (u16)vv[j];
        }
      }
      if (tid < 64) Msk[tid] = mask[bI * NK_ + kbase + tid] ? 0.f : -1e30f;
    }
    __syncthreads();
    // S = Q K^T
    f32x4 sc[4];
#pragma unroll
    for (int t = 0; t < 4; ++t) sc[t] = (f32x4){0.f,0.f,0.f,0.f};
#pragma unroll
    for (int h = 0; h < 2; ++h)
#pragma unroll
      for (int t = 0; t < 4; ++t) {
        int row = t*16 + lb;
        int g = (4*h + la) ^ (row & 7);
        short8 kf = *(const short8*)&Ks[row*64 + g*8];
        sc[t] = __builtin_amdgcn_mfma_f32_16x16x32_bf16(qf[h], kf, sc[t], 0, 0, 0);
      }
    float msk4[4];
#pragma unroll
    for (int t = 0; t < 4; ++t) msk4[t] = Msk[t*16 + lb];
    // online softmax (rows r -> q-local 4*la+r)
    float scl4[4];
    u16 pb[4][4];
#pragma unroll
    for (int r = 0; r < 4; ++r) {
      float sv[4];
#pragma unroll
      for (int t = 0; t < 4; ++t) sv[t] = sc[t][r] * SCALE_ + msk4[t];
      float rm = fmaxf(fmaxf(sv[0], sv[1]), fmaxf(sv[2], sv[3]));
#pragma unroll
      for (int ofs = 1; ofs < 16; ofs <<= 1) rm = fmaxf(rm, __shfl_xor(rm, ofs));
      float mnew = fmaxf(mrow[r], rm);
      float scl = __expf(mrow[r] - mnew);
      mrow[r] = mnew;
      float ps = 0.f;
#pragma unroll
      for (int t = 0; t < 4; ++t) {
        float p = __expf(sv[t] - mnew);
        pb[r][t] = f2bf(p);
        ps += p;
      }
#pragma unroll
      for (int ofs = 1; ofs < 16; ofs <<= 1) ps += __shfl_xor(ps, ofs);
      lrow[r] = lrow[r] * scl + ps;
      scl4[r] = scl;
    }
#pragma unroll
    for (int j = 0; j < 4; ++j)
#pragma unroll
      for (int r = 0; r < 4; ++r) accO[j][r] = accO[j][r] * scl4[r];
    // P -> LDS (per-wave region, swizzled)
#pragma unroll
    for (int r = 0; r < 4; ++r)
#pragma unroll
      for (int t = 0; t < 4; ++t) {
        int q = 4*la + r;
        int key = t*16 + lb;
        Ps[(w*16 + q)*64 + ((((key >> 3) ^ (q & 7)) << 3) | (key & 7))] = pb[r][t];
      }
    // O += P V
#pragma unroll
    for (int kh = 0; kh < 2; ++kh) {
      int pg = (4*kh + la) ^ (lb & 7);
      short8 pf = *(const short8*)&Ps[(w*16 + lb)*64 + pg*8];
#pragma unroll
      for (int j = 0; j < 4; ++j) {
        int d = j*16 + lb;
        int vg = (4*kh + la) ^ (d & 7);
        short8 vf = *(const short8*)&Vt[d*64 + vg*8];
        accO[j] = __builtin_amdgcn_mfma_f32_16x16x32_bf16(pf, vf, accO[j], 0, 0, 0);
      }
    }
  }
  // write partials
  const int qa = qt*64 + w*16;
  const size_t obase = ((size_t)s*16 + bh) * 1024;
#pragma unroll
  for (int j = 0; j < 4; ++j)
#pragma unroll
    for (int r = 0; r < 4; ++r)
      Opart[(obase + qa + 4*la + r) * 64 + j*16 + lb] = accO[j][r];
  if (lb == 0) {
#pragma unroll
    for (int r = 0; r < 4; ++r) {
      mpart[obase + qa + 4*la + r] = mrow[r];
      lpart[obase + qa + 4*la + r] = lrow[r];
    }
  }
}

// ---------------------------------------------------------------- combine partials + rope- -> aob bf16
__global__ __launch_bounds__(256) void combine_kernel(
    const float* __restrict__ Opart, const float* __restrict__ mpart,
    const float* __restrict__ lpart,
    const float* __restrict__ cosq, const float* __restrict__ sinq,
    u16* __restrict__ aob) {
  const int bid = blockIdx.x;     // bh*16 + qt
  const int bh = bid >> 4, qt = bid & 15;
  const int t = threadIdx.x;
  const int ql = t >> 2, ds = (t & 3) << 4;
  const int q = qt*64 + ql;
  const int bI = bh >> 3;
  const size_t rbase = ((size_t)bh << 10) + q;
  float m[SPLITS], li[SPLITS];
  float M = -1e30f;
#pragma unroll
  for (int s = 0; s < SPLITS; ++s) {
    m[s]  = mpart[(size_t)s*16384 + rbase];
    li[s] = lpart[(size_t)s*16384 + rbase];
    M = fmaxf(M, m[s]);
  }
  float ws[SPLITS]; float den = 0.f;
#pragma unroll
  for (int s = 0; s < SPLITS; ++s) { ws[s] = __expf(m[s] - M); den += ws[s]*li[s]; }
  float inv = 1.f / den;
  u16 ob[16];
#pragma unroll
  for (int c = 0; c < 4; ++c) {
    int d0 = ds + 4*c;
    f32x4 o = (f32x4){0.f,0.f,0.f,0.f};
#pragma unroll
    for (int s = 0; s < SPLITS; ++s) {
      f32x4 v = *(const f32x4*)&Opart[((size_t)s*16384 + rbase)*64 + d0];
      o += ws[s] * v;
    }
    o *= inv;
    size_t tix = ((((size_t)bI << 10) + q) << 6) + d0;
    f32x4 cv = *(const f32x4*)&cosq[tix];
    f32x4 sv = *(const f32x4*)&sinq[tix];
    // rope-: y[2i] = x[2i]c + x[2i+1]s ; y[2i+1] = x[2i+1]c - x[2i]s
    ob[4*c+0] = f2bf(o[0]*cv[0] + o[1]*sv[0]);
    ob[4*c+1] = f2bf(o[1]*cv[1] - o[0]*sv[1]);
    ob[4*c+2] = f2bf(o[2]*cv[2] + o[3]*sv[2]);
    ob[4*c+3] = f2bf(o[3]*cv[3] - o[2]*sv[3]);
  }
  u16x8 w0, w1;
#pragma unroll
  for (int j = 0; j < 8; ++j) { w0[j] = ob[j]; w1[j] = ob[8+j]; }
  *(u16x8*)&aob[rbase*64 + ds]     = w0;
  *(u16x8*)&aob[rbase*64 + ds + 8] = w1;
}

// ---------------------------------------------------------------- launch
extern "C" void kernel_launch(void* const* d_in, const int* in_sizes, int n_in,
                              void* d_out, int out_size, void* d_ws, size_t ws_size,
                              hipStream_t stream) {
  (void)in_sizes; (void)n_in; (void)out_size; (void)ws_size;
  const float* xq   = (const float*)d_in[0];
  const float* xc   = (const float*)d_in[1];
  const float* rq   = (const float*)d_in[2];
  const float* rc   = (const float*)d_in[3];
  const int*   mask = (const int*)d_in[4];
  const float* nw   = (const float*)d_in[5];
  const float* nb   = (const float*)d_in[6];
  const float* ncw  = (const float*)d_in[7];
  const float* ncb  = (const float*)d_in[8];
  const float* wq   = (const float*)d_in[9];
  const float* wkv  = (const float*)d_in[10];
  const float* wout = (const float*)d_in[11];
  const float* bout = (const float*)d_in[12];
  float* out = (float*)d_out;

  char* p = (char*)d_ws;
  u16* wqT   = (u16*)p;  p += 524288;
  u16* wkvT  = (u16*)p;  p += 1048576;
  u16* woutT = (u16*)p;  p += 524288;
  u16* xqb   = (u16*)p;  p += 2097152;
  u16* xcb   = (u16*)p;  p += 16777216;   // aliased by Opart after gemm<1>
  float* cosq = (float*)p; p += 524288;
  float* sinq = (float*)p; p += 524288;
  float* cosc = (float*)p; p += 4194304;
  float* sinc = (float*)p; p += 4194304;
  u16* qb = (u16*)p; p += 2097152;
  u16* kb = (u16*)p; p += 16777216;
  u16* vb = (u16*)p; p += 16777216;
  float* mpart = (float*)p; p += 262144;
  float* lpart = (float*)p; p += 262144;
  u16* aob = (u16*)p; p += 2097152;
  float* Opart = (float*)xcb;   // lifetime-disjoint alias (exactly 16777216 B each)

  wt_kernel<<<dim3(256), dim3(256), 0, stream>>>(wq, wkv, wout, wqT, wkvT, woutT);
  ln_kernel<<<dim3(4608), dim3(256), 0, stream>>>(xq, xc, nw, nb, ncw, ncb, xqb, xcb);
  trig_kernel<<<dim3(4096), dim3(256), 0, stream>>>(rq, rc, cosq, sinq, cosc, sinc);
  gemm_mfma<0><<<dim3((2048/64)*(512/64)), dim3(256), 0, stream>>>(
      xqb, wqT, cosq, sinq, nullptr, qb, nullptr, nullptr);
  gemm_mfma<1><<<dim3((16384/128)*(1024/128)), dim3(256), 0, stream>>>(
      xcb, wkvT, cosc, sinc, nullptr, kb, vb, nullptr);
  attn_mfma<<<dim3(16*16*SPLITS), dim3(256), 0, stream>>>(
      qb, kb, vb, mask, Opart, mpart, lpart);
  combine_kernel<<<dim3(256), dim3(256), 0, stream>>>(
      Opart, mpart, lpart, cosq, sinq, aob);
  gemm_mfma<2><<<dim3((2048/64)*(512/64)), dim3(256), 0, stream>>>(
      aob, woutT, nullptr, nullptr, bout, nullptr, nullptr, out);
}

// Round 3
// 238.783 us; speedup vs baseline: 1.4363x; 1.4363x over previous
//
#include <hip/hip_runtime.h>
#include <math.h>

typedef __attribute__((ext_vector_type(8))) short  short8;
typedef __attribute__((ext_vector_type(4))) float  f32x4;
typedef __attribute__((ext_vector_type(4))) unsigned short u16x4;
typedef __attribute__((ext_vector_type(8))) unsigned short u16x8;
typedef unsigned short u16;

#define B_     2
#define NQ_    1024
#define NK_    8192
#define DIM_   512
#define H_     8
#define DH_    64
#define EPS_   1e-5f
#define SCALE_ 0.125f
#define SPLITS 4

__device__ __forceinline__ u16 f2bf(float f) {
  unsigned int u = __float_as_uint(f);
  u += 0x7fffu + ((u >> 16) & 1u);
  return (u16)(u >> 16);
}

// ---------------------------------------------------------------- weight transpose+cast
__global__ __launch_bounds__(256) void wt_kernel(
    const float* __restrict__ wq, const float* __restrict__ wkv,
    const float* __restrict__ wout,
    u16* __restrict__ wqT, u16* __restrict__ wkvT, u16* __restrict__ woutT) {
  __shared__ float tile[64][65];
  int bid = blockIdx.x;
  const float* W; u16* WT; int N; int tix;
  if (bid < 64)       { W = wq;   WT = wqT;   N = 512;  tix = bid; }
  else if (bid < 192) { W = wkv;  WT = wkvT;  N = 1024; tix = bid - 64; }
  else                { W = wout; WT = woutT; N = 512;  tix = bid - 192; }
  int ntn = N >> 6;
  int k0 = (tix / ntn) << 6, n0 = (tix % ntn) << 6;
  int t = threadIdx.x;
  {
    int kk = t >> 2, nc = (t & 3) << 4;
#pragma unroll
    for (int i = 0; i < 4; ++i) {
      f32x4 v = *(const f32x4*)&W[(size_t)(k0 + kk) * N + n0 + nc + 4 * i];
      tile[kk][nc + 4*i + 0] = v[0];
      tile[kk][nc + 4*i + 1] = v[1];
      tile[kk][nc + 4*i + 2] = v[2];
      tile[kk][nc + 4*i + 3] = v[3];
    }
  }
  __syncthreads();
  {
    int n = t >> 2, kc = (t & 3) << 4;
#pragma unroll
    for (int i = 0; i < 2; ++i) {
      u16x8 o;
#pragma unroll
      for (int j = 0; j < 8; ++j) o[j] = f2bf(tile[kc + 8*i + j][n]);
      *(u16x8*)&WT[(size_t)(n0 + n) * 512 + k0 + kc + 8*i] = o;
    }
  }
}

// ---------------------------------------------------------------- LN -> bf16
__global__ __launch_bounds__(256) void ln_kernel(
    const float* __restrict__ xq, const float* __restrict__ xc,
    const float* __restrict__ nw, const float* __restrict__ nb,
    const float* __restrict__ ncw, const float* __restrict__ ncb,
    u16* __restrict__ xqb, u16* __restrict__ xcb) {
  int wid = threadIdx.x >> 6, lane = threadIdx.x & 63;
  int row = blockIdx.x * 4 + wid;
  const float* x; const float* w; const float* bb; u16* o; int r;
  if (row < 2048) { x = xq; w = nw;  bb = nb;  o = xqb; r = row; }
  else            { x = xc; w = ncw; bb = ncb; o = xcb; r = row - 2048; }
  const f32x4* px = (const f32x4*)(x + (size_t)r * 512);
  f32x4 v0 = px[lane], v1 = px[lane + 64];
  float s  = v0[0]+v0[1]+v0[2]+v0[3] + v1[0]+v1[1]+v1[2]+v1[3];
  float ss = v0[0]*v0[0]+v0[1]*v0[1]+v0[2]*v0[2]+v0[3]*v0[3]
           + v1[0]*v1[0]+v1[1]*v1[1]+v1[2]*v1[2]+v1[3]*v1[3];
#pragma unroll
  for (int ofs = 32; ofs >= 1; ofs >>= 1) { s += __shfl_xor(s, ofs); ss += __shfl_xor(ss, ofs); }
  float mu = s * (1.f/512.f);
  float var = ss * (1.f/512.f) - mu*mu;
  float rs = rsqrtf(var + EPS_);
  const f32x4* pw = (const f32x4*)w; const f32x4* pb = (const f32x4*)bb;
#pragma unroll
  for (int seg = 0; seg < 2; ++seg) {
    int e4 = lane + 64*seg;
    f32x4 xv = seg ? v1 : v0;
    f32x4 wv = pw[e4], bv = pb[e4];
    u16x4 ov;
#pragma unroll
    for (int c = 0; c < 4; ++c) ov[c] = f2bf((xv[c]-mu)*rs*wv[c] + bv[c]);
    *(u16x4*)&o[(size_t)r*512 + e4*4] = ov;
  }
}

// ---------------------------------------------------------------- trig tables
__global__ __launch_bounds__(256) void trig_kernel(
    const float* __restrict__ rq, const float* __restrict__ rc,
    float* __restrict__ cq, float* __restrict__ sq,
    float* __restrict__ cc, float* __restrict__ sc) {
  int i = blockIdx.x * 256 + threadIdx.x;
  const int NQE = B_*NQ_*DH_;
  const int NCE = B_*NK_*DH_;
  if (i < NQE) { float s, c; sincosf(rq[i], &s, &c); cq[i] = c; sq[i] = s; }
  if (i < NCE) { float s, c; sincosf(rc[i], &s, &c); cc[i] = c; sc[i] = s; }
}

// ---------------------------------------------------------------- MFMA GEMM
// MODE 0: xqb(2048x512) x wqT   -> rope+, *SCALE -> qb  (bh,seq,64) bf16
// MODE 1: xcb(16384x512) x wkvT -> rope+ -> kb [bh][key][64] ; vtg [bh][d][8192] (transposed)
// MODE 2: aob(remap 2048x512) x woutT + bias -> d_out fp32
template<int MODE>
__global__ __launch_bounds__(256) void gemm_mfma(
    const u16* __restrict__ Abf, const u16* __restrict__ WT,
    const float* __restrict__ ctab, const float* __restrict__ stab,
    const float* __restrict__ bias,
    u16* __restrict__ out0, u16* __restrict__ out1, float* __restrict__ outf) {
  constexpr int BM   = (MODE==1) ? 128 : 64;
  constexpr int BN   = (MODE==1) ? 128 : 32;
  constexpr int MR   = BM/64;
  constexpr int NR   = BN/16;
  constexpr int N    = (MODE==1) ? 1024 : 512;
  constexpr int NSEQ = (MODE==1) ? 8192 : 1024;
  constexpr int NBN  = N / BN;
  constexpr int NWG  = (((MODE==1)?16384:2048)/BM) * NBN;
  __shared__ u16 As[BM*64];
  __shared__ u16 Bs[BN*64];
  const int tid = threadIdx.x;
  const int w = tid >> 6, l = tid & 63;
  const int la = l >> 4, lb = l & 15;
  int bid = blockIdx.x;
  bid = (bid & 7) * (NWG/8) + (bid >> 3);     // XCD chunk swizzle (NWG%8==0)
  const int m0 = (bid / NBN) * BM;
  const int n0 = (bid % NBN) * BN;
  f32x4 acc[MR][NR];
#pragma unroll
  for (int i = 0; i < MR; ++i)
#pragma unroll
    for (int j = 0; j < NR; ++j) acc[i][j] = (f32x4){0.f,0.f,0.f,0.f};

  constexpr int APT = BM/32;              // A granules per thread
  constexpr int BPT = BN/32;              // B granules per thread
  const int arow = tid / (8/APT);
  const int ag0  = (tid % (8/APT)) * APT;
  const int brow = tid / (8/BPT);
  const int bg0  = (tid % (8/BPT)) * BPT;

  for (int k0 = 0; k0 < 512; k0 += 64) {
    if (k0) __syncthreads();
#pragma unroll
    for (int i = 0; i < APT; ++i) {
      int g = ag0 + i;
      short8 av;
      if (MODE == 2) {
        int kk = k0 + g*8;
        int m = m0 + arow;
        av = *(const short8*)&Abf[((size_t)((m >> 10)*H_ + (kk >> 6)) * NQ_ + (m & 1023)) * 64 + (kk & 63)];
      } else {
        av = *(const short8*)&Abf[(size_t)(m0 + arow) * 512 + k0 + g*8];
      }
      *(short8*)&As[arow*64 + ((g ^ (arow & 7)) << 3)] = av;
    }
#pragma unroll
    for (int i = 0; i < BPT; ++i) {
      int g = bg0 + i;
      short8 bv = *(const short8*)&WT[(size_t)(n0 + brow) * 512 + k0 + g*8];
      *(short8*)&Bs[brow*64 + ((g ^ (brow & 7)) << 3)] = bv;
    }
    __syncthreads();
#pragma unroll
    for (int h = 0; h < 2; ++h) {
      short8 af[MR], bfr[NR];
#pragma unroll
      for (int i = 0; i < MR; ++i) {
        int row = w*(16*MR) + i*16 + lb;
        int g = (4*h + la) ^ (row & 7);
        af[i] = *(const short8*)&As[row*64 + g*8];
      }
#pragma unroll
      for (int j = 0; j < NR; ++j) {
        int row = j*16 + lb;
        int g = (4*h + la) ^ (row & 7);
        bfr[j] = *(const short8*)&Bs[row*64 + g*8];
      }
#pragma unroll
      for (int i = 0; i < MR; ++i)
#pragma unroll
        for (int j = 0; j < NR; ++j)
          acc[i][j] = __builtin_amdgcn_mfma_f32_16x16x32_bf16(af[i], bfr[j], acc[i][j], 0, 0, 0);
    }
  }

  // ---- epilogue
  if (MODE == 2) {
#pragma unroll
    for (int i = 0; i < MR; ++i)
#pragma unroll
      for (int j = 0; j < NR; ++j) {
        int n = n0 + 16*j + lb;
        float bv = bias[n];
#pragma unroll
        for (int r = 0; r < 4; ++r) {
          int m = m0 + w*(16*MR) + 16*i + 4*la + r;
          outf[(size_t)m * 512 + n] = acc[i][j][r] + bv;
        }
      }
  } else if (MODE == 1 && n0 >= 512) {
    // V half: rope+, write transposed [bh][d][key] packed over seq
#pragma unroll
    for (int i = 0; i < MR; ++i)
#pragma unroll
      for (int j = 0; j < NR; ++j) {
        int n = n0 + 16*j + lb;
        int e = n - 512, hh = e >> 6, dh = e & 63;
        int mbase = m0 + w*(16*MR) + 16*i + 4*la;
        int bI = mbase / NSEQ;
        int seq = mbase - bI*NSEQ;
        u16x4 pk4;
#pragma unroll
        for (int r = 0; r < 4; ++r) {
          int m = mbase + r;
          float x = acc[i][j][r];
          float pr = __shfl_xor(x, 1);
          float cv = ctab[(size_t)m*64 + dh];
          float sv = stab[(size_t)m*64 + dh];
          pk4[r] = f2bf(x*cv + ((n & 1) ? pr*sv : -pr*sv));
        }
        *(u16x4*)&out1[((size_t)(bI*H_ + hh)*64 + dh)*8192 + seq] = pk4;
      }
  } else {
    // Q / K half: rope+, row-major [bh][seq][64]; SCALE folded for MODE 0
#pragma unroll
    for (int i = 0; i < MR; ++i)
#pragma unroll
      for (int j = 0; j < NR; ++j) {
        int n = n0 + 16*j + lb;
        int hh = n >> 6, dh = n & 63;
#pragma unroll
        for (int r = 0; r < 4; ++r) {
          int m = m0 + w*(16*MR) + 16*i + 4*la + r;
          float x = acc[i][j][r];
          float pr = __shfl_xor(x, 1);
          float cv = ctab[(size_t)m*64 + dh];
          float sv = stab[(size_t)m*64 + dh];
          float y = x*cv + ((n & 1) ? pr*sv : -pr*sv);
          if (MODE == 0) y *= SCALE_;
          int bI = m / NSEQ, seq = m % NSEQ;
          out0[((size_t)(bI*H_ + hh) * NSEQ + seq) * 64 + dh] = f2bf(y);
        }
      }
  }
}

// ---------------------------------------------------------------- attention (swapped-QK MFMA, K-split flash)
// grid = 16 bh * 16 qt * SPLITS (XCD-swizzled). 4 waves, wave owns 16 q-rows.
__global__ __launch_bounds__(256) void attn_mfma(
    const u16* __restrict__ qb, const u16* __restrict__ kb,
    const u16* __restrict__ vtg, const int* __restrict__ mask,
    float* __restrict__ Opart, float* __restrict__ mpart, float* __restrict__ lpart) {
  __shared__ u16 Ks[64*64];       // [key][d] swizzled
  __shared__ u16 Vt[64*64];       // [d][key] swizzled
  __shared__ u16 Ps[4*16*64];     // per-wave [q][key] swizzled
  __shared__ float Mskf[2048];    // whole split's mask as 0 / -1e30
  int bid = blockIdx.x;
  bid = (bid & 7) * 128 + (bid >> 3);          // XCD chunk swizzle (1024 wg)
  const int s  = bid & (SPLITS-1);
  const int qt = (bid >> 2) & 15;
  const int bh = bid >> 6;
  const int bI = bh >> 3;
  const int tid = threadIdx.x;
  const int w = tid >> 6, l = tid & 63;
  const int la = l >> 4, lb = l & 15;
  const int key0 = s * (NK_/SPLITS);           // 2048-key split

  // stage mask for whole split
#pragma unroll
  for (int i = 0; i < 8; ++i)
    Mskf[i*256 + tid] = mask[bI*NK_ + key0 + i*256 + tid] ? 0.f : -1e30f;

  // Q fragments (B operand; SCALE pre-folded)
  const int qrow = qt*64 + w*16 + lb;
  short8 qf0 = *(const short8*)&qb[(((size_t)bh * NQ_) + qrow) * 64 + 8*la];
  short8 qf1 = *(const short8*)&qb[(((size_t)bh * NQ_) + qrow) * 64 + 32 + 8*la];

  // staging map: thread -> (row, 2 granules)
  const int krow = tid >> 2;
  const int kg0  = (tid & 3) * 2;
  const u16* kptr = kb  + ((size_t)bh * NK_ + key0 + krow) * 64;
  const u16* vptr = vtg + ((size_t)bh * 64 + krow) * 8192 + key0;

  short8 kpre0 = *(const short8*)&kptr[(kg0+0)*8];
  short8 kpre1 = *(const short8*)&kptr[(kg0+1)*8];
  short8 vpre0 = *(const short8*)&vptr[(kg0+0)*8];
  short8 vpre1 = *(const short8*)&vptr[(kg0+1)*8];

  f32x4 accO[4];
#pragma unroll
  for (int j = 0; j < 4; ++j) accO[j] = (f32x4){0.f,0.f,0.f,0.f};
  float m_run = -1e30f, l_run = 0.f;

  const int ksw = (krow & 7);
  constexpr int NT = (NK_/SPLITS)/64;          // 32 tiles

  for (int kt = 0; kt < NT; ++kt) {
    // write prefetched tile
    *(short8*)&Ks[krow*64 + (((kg0+0) ^ ksw) << 3)] = kpre0;
    *(short8*)&Ks[krow*64 + (((kg0+1) ^ ksw) << 3)] = kpre1;
    *(short8*)&Vt[krow*64 + (((kg0+0) ^ ksw) << 3)] = vpre0;
    *(short8*)&Vt[krow*64 + (((kg0+1) ^ ksw) << 3)] = vpre1;
    if (kt + 1 < NT) {
      kpre0 = *(const short8*)&kptr[(kt+1)*64*64 + (kg0+0)*8];
      kpre1 = *(const short8*)&kptr[(kt+1)*64*64 + (kg0+1)*8];
      vpre0 = *(const short8*)&vptr[(kt+1)*64 + (kg0+0)*8];
      vpre1 = *(const short8*)&vptr[(kt+1)*64 + (kg0+1)*8];
    }
    __syncthreads();

    // S^T = K Q  (A=K rows -> output row=key, col=query=lb)
    f32x4 sc[4];
#pragma unroll
    for (int t = 0; t < 4; ++t) sc[t] = (f32x4){0.f,0.f,0.f,0.f};
#pragma unroll
    for (int t = 0; t < 4; ++t) {
      int row = t*16 + lb;
      int g0 = la ^ (row & 7);
      int g1 = (4 + la) ^ (row & 7);
      short8 kf0 = *(const short8*)&Ks[row*64 + g0*8];
      short8 kf1 = *(const short8*)&Ks[row*64 + g1*8];
      sc[t] = __builtin_amdgcn_mfma_f32_16x16x32_bf16(kf0, qf0, sc[t], 0, 0, 0);
      sc[t] = __builtin_amdgcn_mfma_f32_16x16x32_bf16(kf1, qf1, sc[t], 0, 0, 0);
    }
    // lane (la,lb): P-values for query lb, keys {16t+4la+r}
    float sv[16];
#pragma unroll
    for (int t = 0; t < 4; ++t) {
      f32x4 mk = *(const f32x4*)&Mskf[kt*64 + t*16 + 4*la];
#pragma unroll
      for (int r = 0; r < 4; ++r) sv[4*t+r] = sc[t][r] + mk[r];
    }
    float pmax = sv[0];
#pragma unroll
    for (int i = 1; i < 16; ++i) pmax = fmaxf(pmax, sv[i]);
    pmax = fmaxf(pmax, __shfl_xor(pmax, 16));
    pmax = fmaxf(pmax, __shfl_xor(pmax, 32));
    if (!__all(pmax <= m_run + 8.f)) {         // defer-max (T13)
      float mnew = fmaxf(m_run, pmax);
      float scl = __expf(m_run - mnew);
      m_run = mnew;
      l_run *= scl;
      float sr[4];
#pragma unroll
      for (int r = 0; r < 4; ++r) sr[r] = __shfl(scl, (l & 48) | (4*la + r));
#pragma unroll
      for (int j = 0; j < 4; ++j)
#pragma unroll
        for (int r = 0; r < 4; ++r) accO[j][r] *= sr[r];
    }
    float psum = 0.f;
    u16 pk[16];
#pragma unroll
    for (int i = 0; i < 16; ++i) {
      float p = __expf(sv[i] - m_run);
      psum += p;
      pk[i] = f2bf(p);
    }
    psum += __shfl_xor(psum, 16);
    psum += __shfl_xor(psum, 32);
    l_run += psum;
    // store P [q=lb][key] swizzled, 8B per t
    const int pwofs = ((4*la) & 7);
#pragma unroll
    for (int t = 0; t < 4; ++t) {
      int gst = 2*t + (la >> 1);
      u16x4 p4 = {pk[4*t], pk[4*t+1], pk[4*t+2], pk[4*t+3]};
      *(u16x4*)&Ps[(w*16 + lb)*64 + ((gst ^ (lb & 7)) << 3) + pwofs] = p4;
    }
    // O += P V   (A=P row=query, B=V^T row=d)
#pragma unroll
    for (int kh = 0; kh < 2; ++kh) {
      int pg = (4*kh + la) ^ (lb & 7);
      short8 pf = *(const short8*)&Ps[(w*16 + lb)*64 + pg*8];
#pragma unroll
      for (int j = 0; j < 4; ++j) {
        int d = j*16 + lb;
        int vg = (4*kh + la) ^ (d & 7);
        short8 vf = *(const short8*)&Vt[d*64 + vg*8];
        accO[j] = __builtin_amdgcn_mfma_f32_16x16x32_bf16(pf, vf, accO[j], 0, 0, 0);
      }
    }
    __syncthreads();
  }

  // write partials (query = qa + 4*la + r, d = 16j + lb)
  const int qa = qt*64 + w*16;
  const size_t obase = ((size_t)s*16 + bh) * 1024;
#pragma unroll
  for (int j = 0; j < 4; ++j)
#pragma unroll
    for (int r = 0; r < 4; ++r)
      Opart[(obase + qa + 4*la + r) * 64 + j*16 + lb] = accO[j][r];
  if (la == 0) {
    mpart[obase + qa + lb] = m_run;
    lpart[obase + qa + lb] = l_run;
  }
}

// ---------------------------------------------------------------- combine partials + rope- -> aob bf16
__global__ __launch_bounds__(256) void combine_kernel(
    const float* __restrict__ Opart, const float* __restrict__ mpart,
    const float* __restrict__ lpart,
    const float* __restrict__ cosq, const float* __restrict__ sinq,
    u16* __restrict__ aob) {
  const int bid = blockIdx.x;
  const int bh = bid >> 4, qt = bid & 15;
  const int t = threadIdx.x;
  const int ql = t >> 2, ds = (t & 3) << 4;
  const int q = qt*64 + ql;
  const int bI = bh >> 3;
  const size_t rbase = ((size_t)bh << 10) + q;
  float m[SPLITS], li[SPLITS];
  float M = -1e30f;
#pragma unroll
  for (int s = 0; s < SPLITS; ++s) {
    m[s]  = mpart[(size_t)s*16384 + rbase];
    li[s] = lpart[(size_t)s*16384 + rbase];
    M = fmaxf(M, m[s]);
  }
  float ws[SPLITS]; float den = 0.f;
#pragma unroll
  for (int s = 0; s < SPLITS; ++s) { ws[s] = __expf(m[s] - M); den += ws[s]*li[s]; }
  float inv = 1.f / den;
  u16 ob[16];
#pragma unroll
  for (int c = 0; c < 4; ++c) {
    int d0 = ds + 4*c;
    f32x4 o = (f32x4){0.f,0.f,0.f,0.f};
#pragma unroll
    for (int s = 0; s < SPLITS; ++s) {
      f32x4 v = *(const f32x4*)&Opart[((size_t)s*16384 + rbase)*64 + d0];
      o += ws[s] * v;
    }
    o *= inv;
    size_t tix = ((((size_t)bI << 10) + q) << 6) + d0;
    f32x4 cv = *(const f32x4*)&cosq[tix];
    f32x4 sv = *(const f32x4*)&sinq[tix];
    ob[4*c+0] = f2bf(o[0]*cv[0] + o[1]*sv[0]);
    ob[4*c+1] = f2bf(o[1]*cv[1] - o[0]*sv[1]);
    ob[4*c+2] = f2bf(o[2]*cv[2] + o[3]*sv[2]);
    ob[4*c+3] = f2bf(o[3]*cv[3] - o[2]*sv[3]);
  }
  u16x8 w0, w1;
#pragma unroll
  for (int j = 0; j < 8; ++j) { w0[j] = ob[j]; w1[j] = ob[8+j]; }
  *(u16x8*)&aob[rbase*64 + ds]     = w0;
  *(u16x8*)&aob[rbase*64 + ds + 8] = w1;
}

// ---------------------------------------------------------------- launch
extern "C" void kernel_launch(void* const* d_in, const int* in_sizes, int n_in,
                              void* d_out, int out_size, void* d_ws, size_t ws_size,
                              hipStream_t stream) {
  (void)in_sizes; (void)n_in; (void)out_size; (void)ws_size;
  const float* xq   = (const float*)d_in[0];
  const float* xc   = (const float*)d_in[1];
  const float* rq   = (const float*)d_in[2];
  const float* rc   = (const float*)d_in[3];
  const int*   mask = (const int*)d_in[4];
  const float* nw   = (const float*)d_in[5];
  const float* nb   = (const float*)d_in[6];
  const float* ncw  = (const float*)d_in[7];
  const float* ncb  = (const float*)d_in[8];
  const float* wq   = (const float*)d_in[9];
  const float* wkv  = (const float*)d_in[10];
  const float* wout = (const float*)d_in[11];
  const float* bout = (const float*)d_in[12];
  float* out = (float*)d_out;

  char* p = (char*)d_ws;
  u16* wqT   = (u16*)p;  p += 524288;
  u16* wkvT  = (u16*)p;  p += 1048576;
  u16* woutT = (u16*)p;  p += 524288;
  u16* xqb   = (u16*)p;  p += 2097152;
  u16* xcb   = (u16*)p;  p += 16777216;   // aliased by Opart after gemm<1>
  float* cosq = (float*)p; p += 524288;
  float* sinq = (float*)p; p += 524288;
  float* cosc = (float*)p; p += 4194304;
  float* sinc = (float*)p; p += 4194304;
  u16* qb  = (u16*)p; p += 2097152;
  u16* kb  = (u16*)p; p += 16777216;
  u16* vtg = (u16*)p; p += 16777216;      // V transposed [bh][d][key]
  float* mpart = (float*)p; p += 262144;
  float* lpart = (float*)p; p += 262144;
  u16* aob = (u16*)p; p += 2097152;
  float* Opart = (float*)xcb;             // lifetime-disjoint alias

  wt_kernel<<<dim3(256), dim3(256), 0, stream>>>(wq, wkv, wout, wqT, wkvT, woutT);
  ln_kernel<<<dim3(4608), dim3(256), 0, stream>>>(xq, xc, nw, nb, ncw, ncb, xqb, xcb);
  trig_kernel<<<dim3(4096), dim3(256), 0, stream>>>(rq, rc, cosq, sinq, cosc, sinc);
  gemm_mfma<0><<<dim3(512), dim3(256), 0, stream>>>(
      xqb, wqT, cosq, sinq, nullptr, qb, nullptr, nullptr);
  gemm_mfma<1><<<dim3(1024), dim3(256), 0, stream>>>(
      xcb, wkvT, cosc, sinc, nullptr, kb, vtg, nullptr);
  attn_mfma<<<dim3(16*16*SPLITS), dim3(256), 0, stream>>>(
      qb, kb, vtg, mask, Opart, mpart, lpart);
  combine_kernel<<<dim3(256), dim3(256), 0, stream>>>(
      Opart, mpart, lpart, cosq, sinq, aob);
  gemm_mfma<2><<<dim3(512), dim3(256), 0, stream>>>(
      aob, woutT, nullptr, nullptr, bout, nullptr, nullptr, out);
}

// Round 6
// 213.021 us; speedup vs baseline: 1.6100x; 1.1209x over previous
//
#include <hip/hip_runtime.h>
#include <math.h>

typedef __attribute__((ext_vector_type(8))) short  short8;
typedef __attribute__((ext_vector_type(4))) float  f32x4;
typedef __attribute__((ext_vector_type(4))) unsigned short u16x4;
typedef __attribute__((ext_vector_type(8))) unsigned short u16x8;
typedef unsigned short u16;

#define B_     2
#define NQ_    1024
#define NK_    8192
#define DIM_   512
#define H_     8
#define DH_    64
#define EPS_   1e-5f
#define SCALE_ 0.125f
#define LOG2E_ 1.4426950408889634f
#define SPLITS 4

__device__ __forceinline__ u16 f2bf(float f) {
  unsigned int u = __float_as_uint(f);
  u += 0x7fffu + ((u >> 16) & 1u);
  return (u16)(u >> 16);
}
__device__ __forceinline__ float fmax3(float a, float b, float c) {
  return fmaxf(fmaxf(a, b), c);   // fuses to v_max3_f32
}

// ---------------------------------------------------------------- weight transpose+cast
__global__ __launch_bounds__(256) void wt_kernel(
    const float* __restrict__ wq, const float* __restrict__ wkv,
    const float* __restrict__ wout,
    u16* __restrict__ wqT, u16* __restrict__ wkvT, u16* __restrict__ woutT) {
  __shared__ float tile[64][65];
  int bid = blockIdx.x;
  const float* W; u16* WT; int N; int tix;
  if (bid < 64)       { W = wq;   WT = wqT;   N = 512;  tix = bid; }
  else if (bid < 192) { W = wkv;  WT = wkvT;  N = 1024; tix = bid - 64; }
  else                { W = wout; WT = woutT; N = 512;  tix = bid - 192; }
  int ntn = N >> 6;
  int k0 = (tix / ntn) << 6, n0 = (tix % ntn) << 6;
  int t = threadIdx.x;
  {
    int kk = t >> 2, nc = (t & 3) << 4;
#pragma unroll
    for (int i = 0; i < 4; ++i) {
      f32x4 v = *(const f32x4*)&W[(size_t)(k0 + kk) * N + n0 + nc + 4 * i];
      tile[kk][nc + 4*i + 0] = v[0];
      tile[kk][nc + 4*i + 1] = v[1];
      tile[kk][nc + 4*i + 2] = v[2];
      tile[kk][nc + 4*i + 3] = v[3];
    }
  }
  __syncthreads();
  {
    int n = t >> 2, kc = (t & 3) << 4;
#pragma unroll
    for (int i = 0; i < 2; ++i) {
      u16x8 o;
#pragma unroll
      for (int j = 0; j < 8; ++j) o[j] = f2bf(tile[kc + 8*i + j][n]);
      *(u16x8*)&WT[(size_t)(n0 + n) * 512 + k0 + kc + 8*i] = o;
    }
  }
}

// ---------------------------------------------------------------- LN -> bf16
__global__ __launch_bounds__(256) void ln_kernel(
    const float* __restrict__ xq, const float* __restrict__ xc,
    const float* __restrict__ nw, const float* __restrict__ nb,
    const float* __restrict__ ncw, const float* __restrict__ ncb,
    u16* __restrict__ xqb, u16* __restrict__ xcb) {
  int wid = threadIdx.x >> 6, lane = threadIdx.x & 63;
  int row = blockIdx.x * 4 + wid;
  const float* x; const float* w; const float* bb; u16* o; int r;
  if (row < 2048) { x = xq; w = nw;  bb = nb;  o = xqb; r = row; }
  else            { x = xc; w = ncw; bb = ncb; o = xcb; r = row - 2048; }
  const f32x4* px = (const f32x4*)(x + (size_t)r * 512);
  f32x4 v0 = px[lane], v1 = px[lane + 64];
  float s  = v0[0]+v0[1]+v0[2]+v0[3] + v1[0]+v1[1]+v1[2]+v1[3];
  float ss = v0[0]*v0[0]+v0[1]*v0[1]+v0[2]*v0[2]+v0[3]*v0[3]
           + v1[0]*v1[0]+v1[1]*v1[1]+v1[2]*v1[2]+v1[3]*v1[3];
#pragma unroll
  for (int ofs = 32; ofs >= 1; ofs >>= 1) { s += __shfl_xor(s, ofs); ss += __shfl_xor(ss, ofs); }
  float mu = s * (1.f/512.f);
  float var = ss * (1.f/512.f) - mu*mu;
  float rs = rsqrtf(var + EPS_);
  const f32x4* pw = (const f32x4*)w; const f32x4* pb = (const f32x4*)bb;
#pragma unroll
  for (int seg = 0; seg < 2; ++seg) {
    int e4 = lane + 64*seg;
    f32x4 xv = seg ? v1 : v0;
    f32x4 wv = pw[e4], bv = pb[e4];
    u16x4 ov;
#pragma unroll
    for (int c = 0; c < 4; ++c) ov[c] = f2bf((xv[c]-mu)*rs*wv[c] + bv[c]);
    *(u16x4*)&o[(size_t)r*512 + e4*4] = ov;
  }
}

// ---------------------------------------------------------------- trig tables
__global__ __launch_bounds__(256) void trig_kernel(
    const float* __restrict__ rq, const float* __restrict__ rc,
    float* __restrict__ cq, float* __restrict__ sq,
    float* __restrict__ cc, float* __restrict__ sc) {
  int i = blockIdx.x * 256 + threadIdx.x;
  const int NQE = B_*NQ_*DH_;
  const int NCE = B_*NK_*DH_;
  if (i < NQE) { float s, c; sincosf(rq[i], &s, &c); cq[i] = c; sq[i] = s; }
  if (i < NCE) { float s, c; sincosf(rc[i], &s, &c); cc[i] = c; sc[i] = s; }
}

// ---------------------------------------------------------------- MFMA GEMM (reg-prefetch dbuf)
// MODE 0: xqb x wqT  -> rope+, *SCALE*LOG2E -> qb
// MODE 1: xcb x wkvT -> rope+ -> kb [bh][key][64] ; vtg [bh][d][8192]
// MODE 2: aob x woutT + bias -> d_out fp32
template<int MODE>
__global__ __launch_bounds__(256) void gemm_mfma(
    const u16* __restrict__ Abf, const u16* __restrict__ WT,
    const float* __restrict__ ctab, const float* __restrict__ stab,
    const float* __restrict__ bias,
    u16* __restrict__ out0, u16* __restrict__ out1, float* __restrict__ outf) {
  constexpr int BM   = (MODE==1) ? 128 : 64;
  constexpr int BN   = (MODE==1) ? 128 : 32;
  constexpr int MR   = BM/64;
  constexpr int NR   = BN/16;
  constexpr int N    = (MODE==1) ? 1024 : 512;
  constexpr int NSEQ = (MODE==1) ? 8192 : 1024;
  constexpr int NBN  = N / BN;
  constexpr int NWG  = (((MODE==1)?16384:2048)/BM) * NBN;
  __shared__ u16 As[BM*64];
  __shared__ u16 Bs[BN*64];
  const int tid = threadIdx.x;
  const int w = tid >> 6, l = tid & 63;
  const int la = l >> 4, lb = l & 15;
  int bid = blockIdx.x;
  bid = (bid & 7) * (NWG/8) + (bid >> 3);
  const int m0 = (bid / NBN) * BM;
  const int n0 = (bid % NBN) * BN;
  f32x4 acc[MR][NR];
#pragma unroll
  for (int i = 0; i < MR; ++i)
#pragma unroll
    for (int j = 0; j < NR; ++j) acc[i][j] = (f32x4){0.f,0.f,0.f,0.f};

  constexpr int APT = BM/32;
  constexpr int BPT = BN/32;
  const int arow = tid / (8/APT);
  const int ag0  = (tid % (8/APT)) * APT;
  const int brow = tid / (8/BPT);
  const int bg0  = (tid % (8/BPT)) * BPT;

  auto loadA = [&](int k0, int g) -> short8 {
    if (MODE == 2) {
      int kk = k0 + g*8;
      int m = m0 + arow;
      return *(const short8*)&Abf[((size_t)((m >> 10)*H_ + (kk >> 6)) * NQ_ + (m & 1023)) * 64 + (kk & 63)];
    } else {
      return *(const short8*)&Abf[(size_t)(m0 + arow) * 512 + k0 + g*8];
    }
  };

  short8 apre[APT], bpre[BPT];
#pragma unroll
  for (int i = 0; i < APT; ++i) apre[i] = loadA(0, ag0 + i);
#pragma unroll
  for (int i = 0; i < BPT; ++i) bpre[i] = *(const short8*)&WT[(size_t)(n0 + brow) * 512 + (bg0 + i)*8];

  for (int k0 = 0; k0 < 512; k0 += 64) {
    if (k0) __syncthreads();
#pragma unroll
    for (int i = 0; i < APT; ++i) {
      int g = ag0 + i;
      *(short8*)&As[arow*64 + ((g ^ (arow & 7)) << 3)] = apre[i];
    }
#pragma unroll
    for (int i = 0; i < BPT; ++i) {
      int g = bg0 + i;
      *(short8*)&Bs[brow*64 + ((g ^ (brow & 7)) << 3)] = bpre[i];
    }
    if (k0 + 64 < 512) {
#pragma unroll
      for (int i = 0; i < APT; ++i) apre[i] = loadA(k0 + 64, ag0 + i);
#pragma unroll
      for (int i = 0; i < BPT; ++i) bpre[i] = *(const short8*)&WT[(size_t)(n0 + brow) * 512 + (k0+64) + (bg0 + i)*8];
    }
    __syncthreads();
#pragma unroll
    for (int h = 0; h < 2; ++h) {
      short8 af[MR], bfr[NR];
#pragma unroll
      for (int i = 0; i < MR; ++i) {
        int row = w*(16*MR) + i*16 + lb;
        int g = (4*h + la) ^ (row & 7);
        af[i] = *(const short8*)&As[row*64 + g*8];
      }
#pragma unroll
      for (int j = 0; j < NR; ++j) {
        int row = j*16 + lb;
        int g = (4*h + la) ^ (row & 7);
        bfr[j] = *(const short8*)&Bs[row*64 + g*8];
      }
#pragma unroll
      for (int i = 0; i < MR; ++i)
#pragma unroll
        for (int j = 0; j < NR; ++j)
          acc[i][j] = __builtin_amdgcn_mfma_f32_16x16x32_bf16(af[i], bfr[j], acc[i][j], 0, 0, 0);
    }
  }

  // ---- epilogue
  if (MODE == 2) {
#pragma unroll
    for (int i = 0; i < MR; ++i)
#pragma unroll
      for (int j = 0; j < NR; ++j) {
        int n = n0 + 16*j + lb;
        float bv = bias[n];
#pragma unroll
        for (int r = 0; r < 4; ++r) {
          int m = m0 + w*(16*MR) + 16*i + 4*la + r;
          outf[(size_t)m * 512 + n] = acc[i][j][r] + bv;
        }
      }
  } else if (MODE == 1 && n0 >= 512) {
#pragma unroll
    for (int i = 0; i < MR; ++i)
#pragma unroll
      for (int j = 0; j < NR; ++j) {
        int n = n0 + 16*j + lb;
        int e = n - 512, hh = e >> 6, dh = e & 63;
        int mbase = m0 + w*(16*MR) + 16*i + 4*la;
        int bI = mbase / NSEQ;
        int seq = mbase - bI*NSEQ;
        u16x4 pk4;
#pragma unroll
        for (int r = 0; r < 4; ++r) {
          int m = mbase + r;
          float x = acc[i][j][r];
          float pr = __shfl_xor(x, 1);
          float cv = ctab[(size_t)m*64 + dh];
          float sv = stab[(size_t)m*64 + dh];
          pk4[r] = f2bf(x*cv + ((n & 1) ? pr*sv : -pr*sv));
        }
        *(u16x4*)&out1[((size_t)(bI*H_ + hh)*64 + dh)*8192 + seq] = pk4;
      }
  } else {
#pragma unroll
    for (int i = 0; i < MR; ++i)
#pragma unroll
      for (int j = 0; j < NR; ++j) {
        int n = n0 + 16*j + lb;
        int hh = n >> 6, dh = n & 63;
#pragma unroll
        for (int r = 0; r < 4; ++r) {
          int m = m0 + w*(16*MR) + 16*i + 4*la + r;
          float x = acc[i][j][r];
          float pr = __shfl_xor(x, 1);
          float cv = ctab[(size_t)m*64 + dh];
          float sv = stab[(size_t)m*64 + dh];
          float y = x*cv + ((n & 1) ? pr*sv : -pr*sv);
          if (MODE == 0) y *= SCALE_ * LOG2E_;   // exp2-domain prescale
          int bI = m / NSEQ, seq = m % NSEQ;
          out0[((size_t)(bI*H_ + hh) * NSEQ + seq) * 64 + dh] = f2bf(y);
        }
      }
  }
}

// ---------------------------------------------------------------- attention
// grid = 16 bh * 8 qt * SPLITS (XCD-swizzled). 8 waves x 16 q-rows = QBLK 128.
__global__ __launch_bounds__(512) void attn_mfma(
    const u16* __restrict__ qb, const u16* __restrict__ kb,
    const u16* __restrict__ vtg, const int* __restrict__ mask,
    float* __restrict__ Opart, float* __restrict__ mpart, float* __restrict__ lpart) {
  __shared__ u16 Ks[64*64];       // [key][d] swizzled
  __shared__ u16 Vt[64*64];       // [d][key] swizzled
  __shared__ u16 Ps[8*16*64];     // per-wave [q][key] swizzled
  __shared__ float Mskf[2048];
  int bid = blockIdx.x;
  bid = (bid & 7) * 64 + (bid >> 3);           // 512 wg, bijective
  const int s  = bid & (SPLITS-1);
  const int qt = (bid >> 2) & 7;
  const int bh = bid >> 5;
  const int bI = bh >> 3;
  const int tid = threadIdx.x;
  const int w = tid >> 6, l = tid & 63;
  const int la = l >> 4, lb = l & 15;
  const int key0 = s * (NK_/SPLITS);

#pragma unroll
  for (int i = 0; i < 4; ++i)
    Mskf[i*512 + tid] = mask[bI*NK_ + key0 + i*512 + tid] ? 0.f : -1e30f;

  // Q fragments (B operand; SCALE*LOG2E pre-folded)
  const int qrow = qt*128 + w*16 + lb;
  short8 qf0 = *(const short8*)&qb[(((size_t)bh * NQ_) + qrow) * 64 + 8*la];
  short8 qf1 = *(const short8*)&qb[(((size_t)bh * NQ_) + qrow) * 64 + 32 + 8*la];

  // staging: 512 threads, 1 K granule + 1 V granule each
  const int krow = tid >> 3;          // 0..63
  const int kg   = tid & 7;
  const u16* kptr = kb  + ((size_t)bh * NK_ + key0 + krow) * 64;
  const u16* vptr = vtg + ((size_t)bh * 64 + krow) * 8192 + key0;
  short8 kpre = *(const short8*)&kptr[kg*8];
  short8 vpre = *(const short8*)&vptr[kg*8];
  const int ksw = krow & 7;

  f32x4 accO[4];
#pragma unroll
  for (int j = 0; j < 4; ++j) accO[j] = (f32x4){0.f,0.f,0.f,0.f};
  float m_run = -1e30f, l_run = 0.f;
  constexpr int NT = (NK_/SPLITS)/64;          // 32 tiles

  const int pbase = (w*16 + lb)*64;
  const int pwofs = (4*la) & 7;

  for (int kt = 0; kt < NT; ++kt) {
    *(short8*)&Ks[krow*64 + ((kg ^ ksw) << 3)] = kpre;
    *(short8*)&Vt[krow*64 + ((kg ^ ksw) << 3)] = vpre;
    if (kt + 1 < NT) {
      kpre = *(const short8*)&kptr[(kt+1)*4096 + kg*8];
      vpre = *(const short8*)&vptr[(kt+1)*64 + kg*8];
    }
    __syncthreads();

    // S^T = K Q  (output row=key, col=query=lb); scores already in exp2 domain
    f32x4 sc[4];
#pragma unroll
    for (int t = 0; t < 4; ++t) sc[t] = (f32x4){0.f,0.f,0.f,0.f};
    __builtin_amdgcn_s_setprio(1);
#pragma unroll
    for (int t = 0; t < 4; ++t) {
      int row = t*16 + lb;
      int g0 = la ^ (row & 7);
      int g1 = (4 + la) ^ (row & 7);
      short8 kf0 = *(const short8*)&Ks[row*64 + g0*8];
      short8 kf1 = *(const short8*)&Ks[row*64 + g1*8];
      sc[t] = __builtin_amdgcn_mfma_f32_16x16x32_bf16(kf0, qf0, sc[t], 0, 0, 0);
      sc[t] = __builtin_amdgcn_mfma_f32_16x16x32_bf16(kf1, qf1, sc[t], 0, 0, 0);
    }
    __builtin_amdgcn_s_setprio(0);
    float sv[16];
#pragma unroll
    for (int t = 0; t < 4; ++t) {
      f32x4 mk = *(const f32x4*)&Mskf[kt*64 + t*16 + 4*la];
#pragma unroll
      for (int r = 0; r < 4; ++r) sv[4*t+r] = sc[t][r] + mk[r];
    }
    // max via max3 tree, then cross-lane (la groups)
    float a0 = fmax3(sv[0],  sv[1],  sv[2]);
    float a1 = fmax3(sv[3],  sv[4],  sv[5]);
    float a2 = fmax3(sv[6],  sv[7],  sv[8]);
    float a3 = fmax3(sv[9],  sv[10], sv[11]);
    float a4 = fmax3(sv[12], sv[13], sv[14]);
    float pmax = fmaxf(fmax3(a0, a1, a2), fmax3(a3, a4, sv[15]));
    pmax = fmaxf(pmax, __shfl_xor(pmax, 16));
    pmax = fmaxf(pmax, __shfl_xor(pmax, 32));
    if (!__all(pmax <= m_run + 11.f)) {        // defer-max (exp2 units)
      float mnew = fmaxf(m_run, pmax);
      float scl = __builtin_amdgcn_exp2f(m_run - mnew);
      m_run = mnew;
      l_run *= scl;
      float sr[4];
#pragma unroll
      for (int r = 0; r < 4; ++r) sr[r] = __shfl(scl, (l & 48) | (4*la + r));
#pragma unroll
      for (int j = 0; j < 4; ++j)
#pragma unroll
        for (int r = 0; r < 4; ++r) accO[j][r] *= sr[r];
    }
    float p[16];
    float psum = 0.f;
#pragma unroll
    for (int i = 0; i < 16; ++i) {
      p[i] = __builtin_amdgcn_exp2f(sv[i] - m_run);
      psum += p[i];
    }
    psum += __shfl_xor(psum, 16);
    psum += __shfl_xor(psum, 32);
    l_run += psum;
    // P -> LDS via v_cvt_pk_bf16_f32 (2 floats -> packed 2xbf16)
#pragma unroll
    for (int t = 0; t < 4; ++t) {
      int gst = 2*t + (la >> 1);
      uint2 pp;
      asm("v_cvt_pk_bf16_f32 %0, %1, %2" : "=v"(pp.x) : "v"(p[4*t+0]), "v"(p[4*t+1]));
      asm("v_cvt_pk_bf16_f32 %0, %1, %2" : "=v"(pp.y) : "v"(p[4*t+2]), "v"(p[4*t+3]));
      *(uint2*)&Ps[pbase + ((gst ^ (lb & 7)) << 3) + pwofs] = pp;
    }
    // O += P V
    __builtin_amdgcn_s_setprio(1);
#pragma unroll
    for (int kh = 0; kh < 2; ++kh) {
      int pg = (4*kh + la) ^ (lb & 7);
      short8 pf = *(const short8*)&Ps[pbase + pg*8];
#pragma unroll
      for (int j = 0; j < 4; ++j) {
        int d = j*16 + lb;
        int vg = (4*kh + la) ^ (d & 7);
        short8 vf = *(const short8*)&Vt[d*64 + vg*8];
        accO[j] = __builtin_amdgcn_mfma_f32_16x16x32_bf16(pf, vf, accO[j], 0, 0, 0);
      }
    }
    __builtin_amdgcn_s_setprio(0);
    __syncthreads();
  }

  const int qa = qt*128 + w*16;
  const size_t obase = ((size_t)s*16 + bh) * 1024;
#pragma unroll
  for (int j = 0; j < 4; ++j)
#pragma unroll
    for (int r = 0; r < 4; ++r)
      Opart[(obase + qa + 4*la + r) * 64 + j*16 + lb] = accO[j][r];
  if (la == 0) {
    mpart[obase + qa + lb] = m_run;
    lpart[obase + qa + lb] = l_run;
  }
}

// ---------------------------------------------------------------- combine (exp2 units) + rope- -> aob
__global__ __launch_bounds__(256) void combine_kernel(
    const float* __restrict__ Opart, const float* __restrict__ mpart,
    const float* __restrict__ lpart,
    const float* __restrict__ cosq, const float* __restrict__ sinq,
    u16* __restrict__ aob) {
  const int bid = blockIdx.x;
  const int bh = bid >> 4, qt = bid & 15;
  const int t = threadIdx.x;
  const int ql = t >> 2, ds = (t & 3) << 4;
  const int q = qt*64 + ql;
  const int bI = bh >> 3;
  const size_t rbase = ((size_t)bh << 10) + q;
  float m[SPLITS], li[SPLITS];
  float M = -1e30f;
#pragma unroll
  for (int s = 0; s < SPLITS; ++s) {
    m[s]  = mpart[(size_t)s*16384 + rbase];
    li[s] = lpart[(size_t)s*16384 + rbase];
    M = fmaxf(M, m[s]);
  }
  float ws[SPLITS]; float den = 0.f;
#pragma unroll
  for (int s = 0; s < SPLITS; ++s) { ws[s] = __builtin_amdgcn_exp2f(m[s] - M); den += ws[s]*li[s]; }
  float inv = 1.f / den;
  u16 ob[16];
#pragma unroll
  for (int c = 0; c < 4; ++c) {
    int d0 = ds + 4*c;
    f32x4 o = (f32x4){0.f,0.f,0.f,0.f};
#pragma unroll
    for (int s = 0; s < SPLITS; ++s) {
      f32x4 v = *(const f32x4*)&Opart[((size_t)s*16384 + rbase)*64 + d0];
      o += ws[s] * v;
    }
    o *= inv;
    size_t tix = ((((size_t)bI << 10) + q) << 6) + d0;
    f32x4 cv = *(const f32x4*)&cosq[tix];
    f32x4 sv = *(const f32x4*)&sinq[tix];
    ob[4*c+0] = f2bf(o[0]*cv[0] + o[1]*sv[0]);
    ob[4*c+1] = f2bf(o[1]*cv[1] - o[0]*sv[1]);
    ob[4*c+2] = f2bf(o[2]*cv[2] + o[3]*sv[2]);
    ob[4*c+3] = f2bf(o[3]*cv[3] - o[2]*sv[3]);
  }
  u16x8 w0, w1;
#pragma unroll
  for (int j = 0; j < 8; ++j) { w0[j] = ob[j]; w1[j] = ob[8+j]; }
  *(u16x8*)&aob[rbase*64 + ds]     = w0;
  *(u16x8*)&aob[rbase*64 + ds + 8] = w1;
}

// ---------------------------------------------------------------- launch
extern "C" void kernel_launch(void* const* d_in, const int* in_sizes, int n_in,
                              void* d_out, int out_size, void* d_ws, size_t ws_size,
                              hipStream_t stream) {
  (void)in_sizes; (void)n_in; (void)out_size; (void)ws_size;
  const float* xq   = (const float*)d_in[0];
  const float* xc   = (const float*)d_in[1];
  const float* rq   = (const float*)d_in[2];
  const float* rc   = (const float*)d_in[3];
  const int*   mask = (const int*)d_in[4];
  const float* nw   = (const float*)d_in[5];
  const float* nb   = (const float*)d_in[6];
  const float* ncw  = (const float*)d_in[7];
  const float* ncb  = (const float*)d_in[8];
  const float* wq   = (const float*)d_in[9];
  const float* wkv  = (const float*)d_in[10];
  const float* wout = (const float*)d_in[11];
  const float* bout = (const float*)d_in[12];
  float* out = (float*)d_out;

  char* p = (char*)d_ws;
  u16* wqT   = (u16*)p;  p += 524288;
  u16* wkvT  = (u16*)p;  p += 1048576;
  u16* woutT = (u16*)p;  p += 524288;
  u16* xqb   = (u16*)p;  p += 2097152;
  u16* xcb   = (u16*)p;  p += 16777216;   // aliased by Opart after gemm<1>
  float* cosq = (float*)p; p += 524288;
  float* sinq = (float*)p; p += 524288;
  float* cosc = (float*)p; p += 4194304;
  float* sinc = (float*)p; p += 4194304;
  u16* qb  = (u16*)p; p += 2097152;
  u16* kb  = (u16*)p; p += 16777216;
  u16* vtg = (u16*)p; p += 16777216;
  float* mpart = (float*)p; p += 262144;
  float* lpart = (float*)p; p += 262144;
  u16* aob = (u16*)p; p += 2097152;
  float* Opart = (float*)xcb;

  wt_kernel<<<dim3(256), dim3(256), 0, stream>>>(wq, wkv, wout, wqT, wkvT, woutT);
  ln_kernel<<<dim3(4608), dim3(256), 0, stream>>>(xq, xc, nw, nb, ncw, ncb, xqb, xcb);
  trig_kernel<<<dim3(4096), dim3(256), 0, stream>>>(rq, rc, cosq, sinq, cosc, sinc);
  gemm_mfma<0><<<dim3(512), dim3(256), 0, stream>>>(
      xqb, wqT, cosq, sinq, nullptr, qb, nullptr, nullptr);
  gemm_mfma<1><<<dim3(1024), dim3(256), 0, stream>>>(
      xcb, wkvT, cosc, sinc, nullptr, kb, vtg, nullptr);
  attn_mfma<<<dim3(16*8*SPLITS), dim3(512), 0, stream>>>(
      qb, kb, vtg, mask, Opart, mpart, lpart);
  combine_kernel<<<dim3(256), dim3(256), 0, stream>>>(
      Opart, mpart, lpart, cosq, sinq, aob);
  gemm_mfma<2><<<dim3(512), dim3(256), 0, stream>>>(
      aob, woutT, nullptr, nullptr, bout, nullptr, nullptr, out);
}

// Round 9
// 209.185 us; speedup vs baseline: 1.6396x; 1.0183x over previous
//
#include <hip/hip_runtime.h>
#include <math.h>

typedef __attribute__((ext_vector_type(8))) short  short8;
typedef __attribute__((ext_vector_type(4))) float  f32x4;
typedef __attribute__((ext_vector_type(4))) unsigned short u16x4;
typedef __attribute__((ext_vector_type(8))) unsigned short u16x8;
typedef unsigned short u16;

#define B_     2
#define NQ_    1024
#define NK_    8192
#define DIM_   512
#define H_     8
#define DH_    64
#define EPS_   1e-5f
#define SCALE_ 0.125f
#define LOG2E_ 1.4426950408889634f

__device__ __forceinline__ u16 f2bf(float f) {
  unsigned int u = __float_as_uint(f);
  u += 0x7fffu + ((u >> 16) & 1u);
  return (u16)(u >> 16);
}
__device__ __forceinline__ float fmax3(float a, float b, float c) {
  return fmaxf(fmaxf(a, b), c);   // fuses to v_max3_f32
}

// ---------------------------------------------------------------- fused prep
// blocks [0,256): weight transpose+cast | [256,4864): LN->bf16
// [4864,8960): trig tables | [8960,9024): maskf table
__global__ __launch_bounds__(256) void prep_kernel(
    const float* __restrict__ wq, const float* __restrict__ wkv,
    const float* __restrict__ wout,
    const float* __restrict__ xq, const float* __restrict__ xc,
    const float* __restrict__ nw, const float* __restrict__ nb,
    const float* __restrict__ ncw, const float* __restrict__ ncb,
    const float* __restrict__ rq, const float* __restrict__ rc,
    const int* __restrict__ mask,
    u16* __restrict__ wqT, u16* __restrict__ wkvT, u16* __restrict__ woutT,
    u16* __restrict__ xqb, u16* __restrict__ xcb,
    float* __restrict__ cq, float* __restrict__ sq2,
    float* __restrict__ cc, float* __restrict__ sc2,
    float* __restrict__ maskf) {
  __shared__ float tile[64][65];
  const int bid = blockIdx.x;
  const int t = threadIdx.x;
  if (bid < 256) {
    // ---- weight transpose+cast: WT[n][k] = bf16(W[k][n])
    const float* W; u16* WT; int N; int tix;
    if (bid < 64)       { W = wq;   WT = wqT;   N = 512;  tix = bid; }
    else if (bid < 192) { W = wkv;  WT = wkvT;  N = 1024; tix = bid - 64; }
    else                { W = wout; WT = woutT; N = 512;  tix = bid - 192; }
    int ntn = N >> 6;
    int k0 = (tix / ntn) << 6, n0 = (tix % ntn) << 6;
    {
      int kk = t >> 2, nc = (t & 3) << 4;
#pragma unroll
      for (int i = 0; i < 4; ++i) {
        f32x4 v = *(const f32x4*)&W[(size_t)(k0 + kk) * N + n0 + nc + 4 * i];
        tile[kk][nc + 4*i + 0] = v[0];
        tile[kk][nc + 4*i + 1] = v[1];
        tile[kk][nc + 4*i + 2] = v[2];
        tile[kk][nc + 4*i + 3] = v[3];
      }
    }
    __syncthreads();
    {
      int n = t >> 2, kc = (t & 3) << 4;
#pragma unroll
      for (int i = 0; i < 2; ++i) {
        u16x8 o;
#pragma unroll
        for (int j = 0; j < 8; ++j) o[j] = f2bf(tile[kc + 8*i + j][n]);
        *(u16x8*)&WT[(size_t)(n0 + n) * 512 + k0 + kc + 8*i] = o;
      }
    }
  } else if (bid < 4864) {
    // ---- LN -> bf16
    int wid = t >> 6, lane = t & 63;
    int row = (bid - 256) * 4 + wid;
    const float* x; const float* w; const float* bb; u16* o; int r;
    if (row < 2048) { x = xq; w = nw;  bb = nb;  o = xqb; r = row; }
    else            { x = xc; w = ncw; bb = ncb; o = xcb; r = row - 2048; }
    const f32x4* px = (const f32x4*)(x + (size_t)r * 512);
    f32x4 v0 = px[lane], v1 = px[lane + 64];
    float s  = v0[0]+v0[1]+v0[2]+v0[3] + v1[0]+v1[1]+v1[2]+v1[3];
    float ss = v0[0]*v0[0]+v0[1]*v0[1]+v0[2]*v0[2]+v0[3]*v0[3]
             + v1[0]*v1[0]+v1[1]*v1[1]+v1[2]*v1[2]+v1[3]*v1[3];
#pragma unroll
    for (int ofs = 32; ofs >= 1; ofs >>= 1) { s += __shfl_xor(s, ofs); ss += __shfl_xor(ss, ofs); }
    float mu = s * (1.f/512.f);
    float var = ss * (1.f/512.f) - mu*mu;
    float rs = rsqrtf(var + EPS_);
    const f32x4* pw = (const f32x4*)w; const f32x4* pb = (const f32x4*)bb;
#pragma unroll
    for (int seg = 0; seg < 2; ++seg) {
      int e4 = lane + 64*seg;
      f32x4 xv = seg ? v1 : v0;
      f32x4 wv = pw[e4], bv = pb[e4];
      u16x4 ov;
#pragma unroll
      for (int c = 0; c < 4; ++c) ov[c] = f2bf((xv[c]-mu)*rs*wv[c] + bv[c]);
      *(u16x4*)&o[(size_t)r*512 + e4*4] = ov;
    }
  } else if (bid < 8960) {
    // ---- trig tables
    int i = (bid - 4864) * 256 + t;
    const int NQE = B_*NQ_*DH_;
    const int NCE = B_*NK_*DH_;
    if (i < NQE) { float s, c; sincosf(rq[i], &s, &c); cq[i] = c; sq2[i] = s; }
    if (i < NCE) { float s, c; sincosf(rc[i], &s, &c); cc[i] = c; sc2[i] = s; }
  } else {
    // ---- maskf: 0/1 float table [2][8192]
    int i = (bid - 8960) * 256 + t;
    maskf[i] = mask[i] ? 1.f : 0.f;
  }
}

// ---------------------------------------------------------------- MFMA GEMM (reg-prefetch dbuf)
// MODE 0: xqb x wqT  -> rope+, *SCALE*LOG2E -> qb
// MODE 1: xcb x wkvT -> rope+ -> kb [bh][key][64] ; vtg [bh][d][8192] (V rows mask-zeroed)
// MODE 2: aob x woutT + bias -> d_out fp32
template<int MODE>
__global__ __launch_bounds__(256) void gemm_mfma(
    const u16* __restrict__ Abf, const u16* __restrict__ WT,
    const float* __restrict__ ctab, const float* __restrict__ stab,
    const float* __restrict__ bias, const float* __restrict__ mvf,
    u16* __restrict__ out0, u16* __restrict__ out1, float* __restrict__ outf) {
  constexpr int BM   = (MODE==1) ? 128 : 64;
  constexpr int BN   = (MODE==1) ? 128 : 32;
  constexpr int MR   = BM/64;
  constexpr int NR   = BN/16;
  constexpr int N    = (MODE==1) ? 1024 : 512;
  constexpr int NSEQ = (MODE==1) ? 8192 : 1024;
  constexpr int NBN  = N / BN;
  constexpr int NWG  = (((MODE==1)?16384:2048)/BM) * NBN;
  __shared__ u16 As[BM*64];
  __shared__ u16 Bs[BN*64];
  const int tid = threadIdx.x;
  const int w = tid >> 6, l = tid & 63;
  const int la = l >> 4, lb = l & 15;
  int bid = blockIdx.x;
  bid = (bid & 7) * (NWG/8) + (bid >> 3);
  const int m0 = (bid / NBN) * BM;
  const int n0 = (bid % NBN) * BN;
  f32x4 acc[MR][NR];
#pragma unroll
  for (int i = 0; i < MR; ++i)
#pragma unroll
    for (int j = 0; j < NR; ++j) acc[i][j] = (f32x4){0.f,0.f,0.f,0.f};

  constexpr int APT = BM/32;
  constexpr int BPT = BN/32;
  const int arow = tid / (8/APT);
  const int ag0  = (tid % (8/APT)) * APT;
  const int brow = tid / (8/BPT);
  const int bg0  = (tid % (8/BPT)) * BPT;

  auto loadA = [&](int k0, int g) -> short8 {
    if (MODE == 2) {
      int kk = k0 + g*8;
      int m = m0 + arow;
      return *(const short8*)&Abf[((size_t)((m >> 10)*H_ + (kk >> 6)) * NQ_ + (m & 1023)) * 64 + (kk & 63)];
    } else {
      return *(const short8*)&Abf[(size_t)(m0 + arow) * 512 + k0 + g*8];
    }
  };

  short8 apre[APT], bpre[BPT];
#pragma unroll
  for (int i = 0; i < APT; ++i) apre[i] = loadA(0, ag0 + i);
#pragma unroll
  for (int i = 0; i < BPT; ++i) bpre[i] = *(const short8*)&WT[(size_t)(n0 + brow) * 512 + (bg0 + i)*8];

  for (int k0 = 0; k0 < 512; k0 += 64) {
    if (k0) __syncthreads();
#pragma unroll
    for (int i = 0; i < APT; ++i) {
      int g = ag0 + i;
      *(short8*)&As[arow*64 + ((g ^ (arow & 7)) << 3)] = apre[i];
    }
#pragma unroll
    for (int i = 0; i < BPT; ++i) {
      int g = bg0 + i;
      *(short8*)&Bs[brow*64 + ((g ^ (brow & 7)) << 3)] = bpre[i];
    }
    if (k0 + 64 < 512) {
#pragma unroll
      for (int i = 0; i < APT; ++i) apre[i] = loadA(k0 + 64, ag0 + i);
#pragma unroll
      for (int i = 0; i < BPT; ++i) bpre[i] = *(const short8*)&WT[(size_t)(n0 + brow) * 512 + (k0+64) + (bg0 + i)*8];
    }
    __syncthreads();
#pragma unroll
    for (int h = 0; h < 2; ++h) {
      short8 af[MR], bfr[NR];
#pragma unroll
      for (int i = 0; i < MR; ++i) {
        int row = w*(16*MR) + i*16 + lb;
        int g = (4*h + la) ^ (row & 7);
        af[i] = *(const short8*)&As[row*64 + g*8];
      }
#pragma unroll
      for (int j = 0; j < NR; ++j) {
        int row = j*16 + lb;
        int g = (4*h + la) ^ (row & 7);
        bfr[j] = *(const short8*)&Bs[row*64 + g*8];
      }
#pragma unroll
      for (int i = 0; i < MR; ++i)
#pragma unroll
        for (int j = 0; j < NR; ++j)
          acc[i][j] = __builtin_amdgcn_mfma_f32_16x16x32_bf16(af[i], bfr[j], acc[i][j], 0, 0, 0);
    }
  }

  // ---- epilogue
  if (MODE == 2) {
#pragma unroll
    for (int i = 0; i < MR; ++i)
#pragma unroll
      for (int j = 0; j < NR; ++j) {
        int n = n0 + 16*j + lb;
        float bv = bias[n];
#pragma unroll
        for (int r = 0; r < 4; ++r) {
          int m = m0 + w*(16*MR) + 16*i + 4*la + r;
          outf[(size_t)m * 512 + n] = acc[i][j][r] + bv;
        }
      }
  } else if (MODE == 1 && n0 >= 512) {
    // V half: rope+, mask-zero, write transposed [bh][d][key]
#pragma unroll
    for (int i = 0; i < MR; ++i) {
      int mbase = m0 + w*(16*MR) + 16*i + 4*la;
      int bI = mbase >> 13;
      int seq = mbase & 8191;
      f32x4 mkv = *(const f32x4*)&mvf[mbase];
#pragma unroll
      for (int j = 0; j < NR; ++j) {
        int n = n0 + 16*j + lb;
        int e = n - 512, hh = e >> 6, dh = e & 63;
        u16x4 pk4;
#pragma unroll
        for (int r = 0; r < 4; ++r) {
          int m = mbase + r;
          float x = acc[i][j][r];
          float pr = __shfl_xor(x, 1);
          float cv = ctab[(size_t)m*64 + dh];
          float sv = stab[(size_t)m*64 + dh];
          pk4[r] = f2bf((x*cv + ((n & 1) ? pr*sv : -pr*sv)) * mkv[r]);
        }
        *(u16x4*)&out1[((size_t)(bI*H_ + hh)*64 + dh)*8192 + seq] = pk4;
      }
    }
  } else {
#pragma unroll
    for (int i = 0; i < MR; ++i)
#pragma unroll
      for (int j = 0; j < NR; ++j) {
        int n = n0 + 16*j + lb;
        int hh = n >> 6, dh = n & 63;
#pragma unroll
        for (int r = 0; r < 4; ++r) {
          int m = m0 + w*(16*MR) + 16*i + 4*la + r;
          float x = acc[i][j][r];
          float pr = __shfl_xor(x, 1);
          float cv = ctab[(size_t)m*64 + dh];
          float sv = stab[(size_t)m*64 + dh];
          float y = x*cv + ((n & 1) ? pr*sv : -pr*sv);
          if (MODE == 0) y *= SCALE_ * LOG2E_;   // exp2-domain prescale
          int bI = m / NSEQ, seq = m % NSEQ;
          out0[((size_t)(bI*H_ + hh) * NSEQ + seq) * 64 + dh] = f2bf(y);
        }
      }
  }
}

// ---------------------------------------------------------------- attention
// grid = 16 bh * NS splits * 8 qt (XCD-swizzled). 8 waves x 16 q-rows = QBLK 128.
// Mask handled via zeroed V rows + fmaf-masked denominator; max over raw scores.
template<int NS>
__global__ __launch_bounds__(512) void attn_mfma(
    const u16* __restrict__ qb, const u16* __restrict__ kb,
    const u16* __restrict__ vtg, const float* __restrict__ maskf,
    float* __restrict__ Opart, float* __restrict__ mpart, float* __restrict__ lpart) {
  __shared__ u16 Ks[64*64];       // [key][d] swizzled
  __shared__ u16 Vt[64*64];       // [d][key] swizzled
  __shared__ u16 Ps[8*16*64];     // per-wave [q][key] swizzled
  constexpr int NWG = 16*8*NS;
  constexpr int CH  = NWG/8;
  constexpr int LS  = (NS==8) ? 3 : 2;
  int orig = blockIdx.x;
  int wid = (orig & 7) * CH + (orig >> 3);     // bijective (NWG%8==0)
  const int qt = wid & 7;
  const int s  = (wid >> 3) & (NS-1);
  const int bh = wid >> (3 + LS);
  const int bI = bh >> 3;
  const int tid = threadIdx.x;
  const int w = tid >> 6, l = tid & 63;
  const int la = l >> 4, lb = l & 15;
  const int key0 = s * (NK_/NS);

  // Q fragments (B operand; SCALE*LOG2E pre-folded)
  const int qrow = qt*128 + w*16 + lb;
  short8 qf0 = *(const short8*)&qb[(((size_t)bh * NQ_) + qrow) * 64 + 8*la];
  short8 qf1 = *(const short8*)&qb[(((size_t)bh * NQ_) + qrow) * 64 + 32 + 8*la];

  // staging: 512 threads, 1 K granule + 1 V granule each
  const int krow = tid >> 3;          // 0..63
  const int kg   = tid & 7;
  const u16* kptr = kb  + ((size_t)bh * NK_ + key0 + krow) * 64;
  const u16* vptr = vtg + ((size_t)bh * 64 + krow) * 8192 + key0;
  short8 kpre = *(const short8*)&kptr[kg*8];
  short8 vpre = *(const short8*)&vptr[kg*8];
  const int ksw = krow & 7;
  const float* mrow = maskf + bI*8192 + key0 + 4*la;

  f32x4 accO[4];
#pragma unroll
  for (int j = 0; j < 4; ++j) accO[j] = (f32x4){0.f,0.f,0.f,0.f};
  float m_run = -1e30f, l_run = 0.f;
  constexpr int NT = (NK_/NS)/64;

  const int pbase = (w*16 + lb)*64;
  const int pwofs = (4*la) & 7;

  for (int kt = 0; kt < NT; ++kt) {
    *(short8*)&Ks[krow*64 + ((kg ^ ksw) << 3)] = kpre;
    *(short8*)&Vt[krow*64 + ((kg ^ ksw) << 3)] = vpre;
    if (kt + 1 < NT) {
      kpre = *(const short8*)&kptr[(kt+1)*4096 + kg*8];
      vpre = *(const short8*)&vptr[(kt+1)*64 + kg*8];
    }
    __syncthreads();

    // S^T = K Q  (output row=key, col=query=lb); scores in exp2 domain
    f32x4 sc[4];
#pragma unroll
    for (int t = 0; t < 4; ++t) sc[t] = (f32x4){0.f,0.f,0.f,0.f};
    __builtin_amdgcn_s_setprio(1);
#pragma unroll
    for (int t = 0; t < 4; ++t) {
      int row = t*16 + lb;
      int g0 = la ^ (row & 7);
      int g1 = (4 + la) ^ (row & 7);
      short8 kf0 = *(const short8*)&Ks[row*64 + g0*8];
      short8 kf1 = *(const short8*)&Ks[row*64 + g1*8];
      sc[t] = __builtin_amdgcn_mfma_f32_16x16x32_bf16(kf0, qf0, sc[t], 0, 0, 0);
      sc[t] = __builtin_amdgcn_mfma_f32_16x16x32_bf16(kf1, qf1, sc[t], 0, 0, 0);
    }
    __builtin_amdgcn_s_setprio(0);
    // max over raw scores (over-estimate on masked keys is harmless)
    float a0 = fmax3(sc[0][0], sc[0][1], sc[0][2]);
    float a1 = fmax3(sc[0][3], sc[1][0], sc[1][1]);
    float a2 = fmax3(sc[1][2], sc[1][3], sc[2][0]);
    float a3 = fmax3(sc[2][1], sc[2][2], sc[2][3]);
    float a4 = fmax3(sc[3][0], sc[3][1], sc[3][2]);
    float pmax = fmaxf(fmax3(a0, a1, a2), fmax3(a3, a4, sc[3][3]));
    pmax = fmaxf(pmax, __shfl_xor(pmax, 16));
    pmax = fmaxf(pmax, __shfl_xor(pmax, 32));
    if (!__all(pmax <= m_run + 11.f)) {        // defer-max (exp2 units)
      float mnew = fmaxf(m_run, pmax);
      float scl = __builtin_amdgcn_exp2f(m_run - mnew);
      m_run = mnew;
      l_run *= scl;
      float sr[4];
#pragma unroll
      for (int r = 0; r < 4; ++r) sr[r] = __shfl(scl, (l & 48) | (4*la + r));
#pragma unroll
      for (int j = 0; j < 4; ++j)
#pragma unroll
        for (int r = 0; r < 4; ++r) accO[j][r] *= sr[r];
    }
    // exp + masked denominator + P store (merged per-t, low register pressure)
    float l_add = 0.f;
#pragma unroll
    for (int t = 0; t < 4; ++t) {
      f32x4 mk = *(const f32x4*)&mrow[kt*64 + t*16];
      float p0 = __builtin_amdgcn_exp2f(sc[t][0] - m_run);
      float p1 = __builtin_amdgcn_exp2f(sc[t][1] - m_run);
      float p2 = __builtin_amdgcn_exp2f(sc[t][2] - m_run);
      float p3 = __builtin_amdgcn_exp2f(sc[t][3] - m_run);
      l_add = fmaf(p0, mk[0], l_add);
      l_add = fmaf(p1, mk[1], l_add);
      l_add = fmaf(p2, mk[2], l_add);
      l_add = fmaf(p3, mk[3], l_add);
      int gst = 2*t + (la >> 1);
      uint2 pp;
      asm("v_cvt_pk_bf16_f32 %0, %1, %2" : "=v"(pp.x) : "v"(p0), "v"(p1));
      asm("v_cvt_pk_bf16_f32 %0, %1, %2" : "=v"(pp.y) : "v"(p2), "v"(p3));
      *(uint2*)&Ps[pbase + ((gst ^ (lb & 7)) << 3) + pwofs] = pp;
    }
    l_run += l_add;
    // O += P V  (masked keys contribute 0: V rows zeroed)
    __builtin_amdgcn_s_setprio(1);
#pragma unroll
    for (int kh = 0; kh < 2; ++kh) {
      int pg = (4*kh + la) ^ (lb & 7);
      short8 pf = *(const short8*)&Ps[pbase + pg*8];
#pragma unroll
      for (int j = 0; j < 4; ++j) {
        int d = j*16 + lb;
        int vg = (4*kh + la) ^ (d & 7);
        short8 vf = *(const short8*)&Vt[d*64 + vg*8];
        accO[j] = __builtin_amdgcn_mfma_f32_16x16x32_bf16(pf, vf, accO[j], 0, 0, 0);
      }
    }
    __builtin_amdgcn_s_setprio(0);
    __syncthreads();
  }

  // deferred cross-lane l reduction (la groups of same query)
  l_run += __shfl_xor(l_run, 16);
  l_run += __shfl_xor(l_run, 32);

  const int qa = qt*128 + w*16;
  const size_t obase = ((size_t)s*16 + bh) * 1024;
#pragma unroll
  for (int j = 0; j < 4; ++j)
#pragma unroll
    for (int r = 0; r < 4; ++r)
      Opart[(obase + qa + 4*la + r) * 64 + j*16 + lb] = accO[j][r];
  if (la == 0) {
    mpart[obase + qa + lb] = m_run;
    lpart[obase + qa + lb] = l_run;
  }
}

// ---------------------------------------------------------------- combine (exp2 units) + rope- -> aob
template<int NS>
__global__ __launch_bounds__(256) void combine_kernel(
    const float* __restrict__ Opart, const float* __restrict__ mpart,
    const float* __restrict__ lpart,
    const float* __restrict__ cosq, const float* __restrict__ sinq,
    u16* __restrict__ aob) {
  const int bid = blockIdx.x;
  const int bh = bid >> 4, qt = bid & 15;
  const int t = threadIdx.x;
  const int ql = t >> 2, ds = (t & 3) << 4;
  const int q = qt*64 + ql;
  const int bI = bh >> 3;
  const size_t rbase = ((size_t)bh << 10) + q;
  float m[NS], li[NS];
  float M = -1e30f;
#pragma unroll
  for (int s = 0; s < NS; ++s) {
    m[s]  = mpart[(size_t)s*16384 + rbase];
    li[s] = lpart[(size_t)s*16384 + rbase];
    M = fmaxf(M, m[s]);
  }
  float ws[NS]; float den = 0.f;
#pragma unroll
  for (int s = 0; s < NS; ++s) { ws[s] = __builtin_amdgcn_exp2f(m[s] - M); den += ws[s]*li[s]; }
  float inv = 1.f / den;
  u16 ob[16];
#pragma unroll
  for (int c = 0; c < 4; ++c) {
    int d0 = ds + 4*c;
    f32x4 o = (f32x4){0.f,0.f,0.f,0.f};
#pragma unroll
    for (int s = 0; s < NS; ++s) {
      f32x4 v = *(const f32x4*)&Opart[((size_t)s*16384 + rbase)*64 + d0];
      o += ws[s] * v;
    }
    o *= inv;
    size_t tix = ((((size_t)bI << 10) + q) << 6) + d0;
    f32x4 cv = *(const f32x4*)&cosq[tix];
    f32x4 sv = *(const f32x4*)&sinq[tix];
    ob[4*c+0] = f2bf(o[0]*cv[0] + o[1]*sv[0]);
    ob[4*c+1] = f2bf(o[1]*cv[1] - o[0]*sv[1]);
    ob[4*c+2] = f2bf(o[2]*cv[2] + o[3]*sv[2]);
    ob[4*c+3] = f2bf(o[3]*cv[3] - o[2]*sv[3]);
  }
  u16x8 w0, w1;
#pragma unroll
  for (int j = 0; j < 8; ++j) { w0[j] = ob[j]; w1[j] = ob[8+j]; }
  *(u16x8*)&aob[rbase*64 + ds]     = w0;
  *(u16x8*)&aob[rbase*64 + ds + 8] = w1;
}

// ---------------------------------------------------------------- launch
extern "C" void kernel_launch(void* const* d_in, const int* in_sizes, int n_in,
                              void* d_out, int out_size, void* d_ws, size_t ws_size,
                              hipStream_t stream) {
  (void)in_sizes; (void)n_in; (void)out_size;
  const float* xq   = (const float*)d_in[0];
  const float* xc   = (const float*)d_in[1];
  const float* rq   = (const float*)d_in[2];
  const float* rc   = (const float*)d_in[3];
  const int*   mask = (const int*)d_in[4];
  const float* nw   = (const float*)d_in[5];
  const float* nb   = (const float*)d_in[6];
  const float* ncw  = (const float*)d_in[7];
  const float* ncb  = (const float*)d_in[8];
  const float* wq   = (const float*)d_in[9];
  const float* wkv  = (const float*)d_in[10];
  const float* wout = (const float*)d_in[11];
  const float* bout = (const float*)d_in[12];
  float* out = (float*)d_out;

  // ---- workspace layout. Persistent region first; then a pool of buffers
  // dead by attention time, which Opart overlays. Fallback (NS=4) footprint
  // is exactly the round-2..6-proven 68,681,728 B; NS=8 (needs 74.4 MB) is
  // gated on ws_size (constant per deployment -> graph-safe).
  char* p = (char*)d_ws;
  u16*   woutT  = (u16*)p;   p += 524288;
  float* cosq   = (float*)p; p += 524288;
  float* sinq   = (float*)p; p += 524288;
  u16*   qb     = (u16*)p;   p += 2097152;
  u16*   kb     = (u16*)p;   p += 16777216;
  u16*   vtg    = (u16*)p;   p += 16777216;
  float* mpart4 = (float*)p; p += 262144;     // 4-split m/l (fallback)
  float* lpart4 = (float*)p; p += 262144;
  u16*   aob    = (u16*)p;   p += 2097152;
  float* maskf  = (float*)aob;                // overlay: maskf dead before combine writes aob
  char* pool = p;
  u16*   wqT   = (u16*)p;   p += 524288;
  u16*   wkvT  = (u16*)p;   p += 1048576;
  u16*   xqb   = (u16*)p;   p += 2097152;
  u16*   xcb   = (u16*)p;   p += 16777216;
  float* cosc  = (float*)p; p += 4194304;
  float* sinc  = (float*)p; p += 4194304;     // pool = 28,835,840 B
  float* Opart = (float*)pool;                // overlays pool (dead during attn)
  // 8-split m/l live past the 33.5 MB Opart region, inside the gated area
  float* mpart8 = (float*)(pool + 33554432);
  float* lpart8 = (float*)(pool + 33554432 + 524288);
  const size_t need8 = (size_t)(pool - (char*)d_ws) + 33554432ull + 1048576ull;
  const bool use8 = ws_size >= need8;

  prep_kernel<<<dim3(9024), dim3(256), 0, stream>>>(
      wq, wkv, wout, xq, xc, nw, nb, ncw, ncb, rq, rc, mask,
      wqT, wkvT, woutT, xqb, xcb, cosq, sinq, cosc, sinc, maskf);
  gemm_mfma<0><<<dim3(512), dim3(256), 0, stream>>>(
      xqb, wqT, cosq, sinq, nullptr, nullptr, qb, nullptr, nullptr);
  gemm_mfma<1><<<dim3(1024), dim3(256), 0, stream>>>(
      xcb, wkvT, cosc, sinc, nullptr, maskf, kb, vtg, nullptr);
  if (use8) {
    attn_mfma<8><<<dim3(1024), dim3(512), 0, stream>>>(
        qb, kb, vtg, maskf, Opart, mpart8, lpart8);
    combine_kernel<8><<<dim3(256), dim3(256), 0, stream>>>(
        Opart, mpart8, lpart8, cosq, sinq, aob);
  } else {
    attn_mfma<4><<<dim3(512), dim3(512), 0, stream>>>(
        qb, kb, vtg, maskf, Opart, mpart4, lpart4);
    combine_kernel<4><<<dim3(256), dim3(256), 0, stream>>>(
        Opart, mpart4, lpart4, cosq, sinq, aob);
  }
  gemm_mfma<2><<<dim3(512), dim3(256), 0, stream>>>(
      aob, woutT, nullptr, nullptr, bout, nullptr, nullptr, nullptr, out);
}